// Round 3
// baseline (1037.028 us; speedup 1.0000x reference)
//
#include <hip/hip_runtime.h>
#include <hip/hip_bf16.h>

typedef __hip_bfloat16 bf16;
__device__ __forceinline__ float b2f(bf16 v){ return __bfloat162float(v); }
__device__ __forceinline__ bf16 f2b(float v){ return __float2bfloat16(v); }

#define LLEN 3136
#define BATCH 2

// ---------------- dwconv 3x3 + gelu ----------------
__global__ void k_dwconv_gelu(const float* __restrict__ x, const float* __restrict__ dww,
                              const float* __restrict__ dwb, bf16* __restrict__ tmp){
  int bc = blockIdx.x;            // b*128 + c
  int c = bc & 127;
  const float* xp = x + (size_t)bc*LLEN;
  float w[9];
  #pragma unroll
  for (int i=0;i<9;i++) w[i] = dww[c*9+i];
  float bias = dwb[c];
  for (int p = threadIdx.x; p < LLEN; p += blockDim.x){
    int i = p/56, j = p%56;
    float acc = bias;
    #pragma unroll
    for (int a=0;a<3;a++){
      int ii = i + a - 1;
      if (ii < 0 || ii >= 56) continue;
      #pragma unroll
      for (int bb=0;bb<3;bb++){
        int jj = j + bb - 1;
        if (jj < 0 || jj >= 56) continue;
        acc += w[a*3+bb] * xp[ii*56+jj];
      }
    }
    float g = 0.5f*acc*(1.0f + erff(acc*0.70710678118654752f));
    tmp[(size_t)bc*LLEN + p] = f2b(g);
  }
}

// ---------------- pointwise conv GEMM: fused[b,o,p] = sum_c tmp[b,c,p]*pw[o,c] + pb[o] ----------------
__global__ void k_pw_gemm(const bf16* __restrict__ tmp, const float* __restrict__ pww,
                          const float* __restrict__ pwb, float* __restrict__ fused){
  __shared__ __align__(16) float As[16][68];
  __shared__ __align__(16) float Ws[16][68];
  int b = blockIdx.z;
  int p0 = blockIdx.x * 64;
  int n0 = blockIdx.y * 64;
  const bf16* A = tmp + (size_t)b*128*LLEN;
  int tid = threadIdx.x;
  int tx = tid & 15, ty = tid >> 4;
  float acc[4][4] = {};
  for (int k0 = 0; k0 < 128; k0 += 16){
    #pragma unroll
    for (int r=0;r<4;r++){
      int idx = tid + r*256;
      int k = idx >> 6, m = idx & 63;
      As[k][m] = b2f(A[(size_t)(k0+k)*LLEN + p0 + m]);
    }
    #pragma unroll
    for (int r=0;r<4;r++){
      int idx = tid + r*256;
      int k = idx & 15, n = idx >> 4;
      Ws[k][n] = pww[(n0+n)*128 + k0 + k];
    }
    __syncthreads();
    #pragma unroll
    for (int kk=0;kk<16;kk++){
      float4 av = *reinterpret_cast<const float4*>(&As[kk][ty*4]);
      float4 wv = *reinterpret_cast<const float4*>(&Ws[kk][tx*4]);
      float a4[4] = {av.x,av.y,av.z,av.w};
      float w4[4] = {wv.x,wv.y,wv.z,wv.w};
      #pragma unroll
      for (int i=0;i<4;i++)
        #pragma unroll
        for (int j=0;j<4;j++) acc[i][j] += a4[i]*w4[j];
    }
    __syncthreads();
  }
  #pragma unroll
  for (int j=0;j<4;j++){
    int n = n0 + tx*4 + j;
    float bias = pwb[n];
    #pragma unroll
    for (int i=0;i<4;i++){
      fused[((size_t)b*128 + n)*LLEN + p0 + ty*4 + i] = acc[i][j] + bias;
    }
  }
}

// ---------------- LayerNorm over C, write both direction orderings (bf16) ----------------
__global__ void k_ln(const float* __restrict__ x, const float* nhw_, const float* nhb_,
                     const float* nvw_, const float* nvb_, bf16* __restrict__ xln){
  __shared__ float sx[128][57];
  __shared__ float smean[56], srstd[56];
  __shared__ float wh[128], bh[128], wv_[128], bv_[128];
  int h = blockIdx.x; int b = blockIdx.y;
  int tid = threadIdx.x;
  if (tid < 128){ wh[tid]=nhw_[tid]; bh[tid]=nhb_[tid];
                  wv_[tid]=nvw_[tid]; bv_[tid]=nvb_[tid]; }
  for (int idx = tid; idx < 128*56; idx += 256){
    int c = idx / 56, w = idx % 56;
    sx[c][w] = x[((size_t)(b*128+c))*LLEN + h*56 + w];
  }
  __syncthreads();
  if (tid < 56){
    float s=0.f, s2=0.f;
    for (int c=0;c<128;c++){ float v = sx[c][tid]; s+=v; s2+=v*v; }
    float m = s*(1.f/128.f);
    float var = s2*(1.f/128.f) - m*m;
    smean[tid]=m; srstd[tid]=rsqrtf(var+1e-5f);
  }
  __syncthreads();
  bf16* outh = xln;
  bf16* outv = xln + (size_t)BATCH*LLEN*128;
  for (int idx = tid; idx < 56*128; idx += 256){
    int w = idx >> 7, c = idx & 127;
    float v = (sx[c][w]-smean[w])*srstd[w];
    outh[((size_t)b*LLEN + h*56 + w)*128 + c] = f2b(v*wh[c]+bh[c]);
    outv[((size_t)b*LLEN + w*56 + h)*128 + c] = f2b(v*wv_[c]+bv_[c]);
  }
}

// ---------------- in_proj GEMM: M=6272(per dir), N=512, K=128 -> XI (n<256) / Z (n>=256) ----------------
__global__ void k_inproj(const bf16* __restrict__ xln, const float* __restrict__ hw,
                         const float* __restrict__ vw, bf16* __restrict__ XI, bf16* __restrict__ Z){
  int dir = blockIdx.z;
  const bf16* A = xln + (size_t)dir*BATCH*LLEN*128;
  const float* W = dir ? vw : hw;
  int m0 = blockIdx.x*64, n0 = blockIdx.y*64;
  __shared__ __align__(16) float As[16][68];
  __shared__ __align__(16) float Ws[16][68];
  int tid = threadIdx.x, tx = tid&15, ty = tid>>4;
  float acc[4][4] = {};
  for (int k0=0;k0<128;k0+=16){
    #pragma unroll
    for (int r=0;r<4;r++){
      int idx = tid + r*256;
      int row = idx >> 4, k = idx & 15;
      As[k][row] = b2f(A[(size_t)(m0+row)*128 + k0 + k]);
      Ws[k][row] = W[(size_t)(n0+row)*128 + k0 + k];
    }
    __syncthreads();
    #pragma unroll
    for (int kk=0;kk<16;kk++){
      float4 av = *reinterpret_cast<const float4*>(&As[kk][ty*4]);
      float4 wv = *reinterpret_cast<const float4*>(&Ws[kk][tx*4]);
      float a4[4] = {av.x,av.y,av.z,av.w};
      float w4[4] = {wv.x,wv.y,wv.z,wv.w};
      #pragma unroll
      for (int i=0;i<4;i++)
        #pragma unroll
        for (int j=0;j<4;j++) acc[i][j] += a4[i]*w4[j];
    }
    __syncthreads();
  }
  bf16* dst = (n0 < 256) ? XI : Z;
  int nbase = n0 & 255;
  size_t dslab = (size_t)dir*BATCH*LLEN*256;
  #pragma unroll
  for (int i=0;i<4;i++)
    #pragma unroll
    for (int j=0;j<4;j++)
      dst[dslab + (size_t)(m0+ty*4+i)*256 + nbase + tx*4 + j] = f2b(acc[i][j]);
}

// ---------------- causal depthwise conv1d(k=4) + silu ----------------
__global__ void k_conv(const bf16* __restrict__ XI, const float* hw, const float* hb,
                       const float* vw, const float* vb, bf16* __restrict__ XS){
  int dir = blockIdx.z;
  int b = blockIdx.y;
  int l0 = blockIdx.x * 32;
  const bf16* XId = XI + ((size_t)dir*BATCH + b)*LLEN*256;
  bf16* XSd = XS + ((size_t)dir*BATCH + b)*LLEN*256;
  const float* cw = dir ? vw : hw;
  const float* cb = dir ? vb : hb;
  __shared__ float sxi[35][256];
  int tid = threadIdx.x;
  for (int r = 0; r < 35; r++){
    int l = l0 - 3 + r;
    sxi[r][tid] = (l >= 0) ? b2f(XId[(size_t)l*256 + tid]) : 0.f;
  }
  __syncthreads();
  float w0=cw[tid*4], w1=cw[tid*4+1], w2=cw[tid*4+2], w3=cw[tid*4+3];
  float bias = cb[tid];
  for (int ll=0; ll<32; ll++){
    float acc = bias + w0*sxi[ll][tid] + w1*sxi[ll+1][tid] + w2*sxi[ll+2][tid] + w3*sxi[ll+3][tid];
    float s = acc / (1.f + __expf(-acc));
    XSd[(size_t)(l0+ll)*256 + tid] = f2b(s);
  }
}

// ---------------- xproj -> dbl(40); dt = softplus(dbl[:8]@dtw.T + dtb); B,C extract ----------------
__global__ void k_xproj(const bf16* __restrict__ xs, const float* hx, const float* vx,
                        const float* hdw, const float* vdw, const float* hdb, const float* vdb,
                        bf16* __restrict__ dt, float* __restrict__ Bc, float* __restrict__ Cc){
  int dir = blockIdx.y;
  int m = blockIdx.x;          // b*L + l
  const bf16* xrow = xs + (size_t)dir*BATCH*LLEN*256 + (size_t)m*256;
  const float* xw  = dir ? vx : hx;
  const float* dtw = dir ? vdw : hdw;
  const float* dtb = dir ? vdb : hdb;
  __shared__ float sx[256];
  __shared__ float sdbl[40];
  int tid = threadIdx.x;
  sx[tid] = b2f(xrow[tid]);
  __syncthreads();
  int wv = tid >> 6, lane = tid & 63;
  #pragma unroll
  for (int oi = 0; oi < 10; oi++){
    int o = wv*10 + oi;
    float p = sx[lane]      * xw[o*256+lane]
            + sx[lane+64]   * xw[o*256+lane+64]
            + sx[lane+128]  * xw[o*256+lane+128]
            + sx[lane+192]  * xw[o*256+lane+192];
    #pragma unroll
    for (int off=32; off>0; off>>=1) p += __shfl_down(p, off, 64);
    if (lane == 0) sdbl[o] = p;
  }
  __syncthreads();
  float a = dtb[tid];
  #pragma unroll
  for (int r=0;r<8;r++) a += sdbl[r]*dtw[tid*8+r];
  float sp = (a > 20.f) ? a : __logf(1.f + __expf(a));
  dt[(size_t)dir*BATCH*LLEN*256 + (size_t)m*256 + tid] = f2b(sp);
  if (tid < 16)      Bc[(size_t)dir*BATCH*LLEN*16 + (size_t)m*16 + tid] = sdbl[8+tid];
  else if (tid < 32) Cc[(size_t)dir*BATCH*LLEN*16 + (size_t)m*16 + (tid-16)] = sdbl[24+(tid-16)];
}

// ---------------- selective scan ----------------
__global__ void k_scan(const bf16* __restrict__ dt, const bf16* __restrict__ xs,
                       const float* __restrict__ Bc, const float* __restrict__ Cc,
                       const float* hA, const float* vA, bf16* __restrict__ ys){
  int dir = blockIdx.z;
  int b = blockIdx.y;
  int g = blockIdx.x;     // channel group 0..15
  const bf16* dtd = dt + ((size_t)dir*BATCH + b)*LLEN*256;
  const bf16* xsd = xs + ((size_t)dir*BATCH + b)*LLEN*256;
  const float* Bd  = Bc + ((size_t)dir*BATCH + b)*LLEN*16;
  const float* Cd  = Cc + ((size_t)dir*BATCH + b)*LLEN*16;
  bf16* yd = ys + ((size_t)dir*BATCH + b)*LLEN*256;
  const float* Alog = dir ? vA : hA;
  int tid = threadIdx.x;
  int dl = tid >> 4, n = tid & 15;
  int d = g*16 + dl;
  float A = -__expf(Alog[d*16+n]);
  __shared__ float sdt[64][16], sxs[64][16], sB[64][16], sC[64][16];
  float h = 0.f;
  for (int l0 = 0; l0 < LLEN; l0 += 64){
    __syncthreads();
    #pragma unroll
    for (int r=0;r<4;r++){
      int idx = tid + r*256;
      int i = idx >> 4, j = idx & 15;
      sdt[i][j] = b2f(dtd[(size_t)(l0+i)*256 + g*16 + j]);
      sxs[i][j] = b2f(xsd[(size_t)(l0+i)*256 + g*16 + j]);
      (&sB[0][0])[idx] = Bd[(size_t)l0*16 + idx];
      (&sC[0][0])[idx] = Cd[(size_t)l0*16 + idx];
    }
    __syncthreads();
    #pragma unroll 8
    for (int i=0;i<64;i++){
      float a = sdt[i][dl];
      float u = sxs[i][dl];
      float dA = __expf(a * A);
      h = dA*h + (a*u)*sB[i][n];
      float p = h * sC[i][n];
      p += __shfl_xor(p, 1, 16);
      p += __shfl_xor(p, 2, 16);
      p += __shfl_xor(p, 4, 16);
      p += __shfl_xor(p, 8, 16);
      if (n == 0) yd[(size_t)(l0+i)*256 + d] = f2b(p);
    }
  }
}

// ---------------- out_proj + gating, accumulate into fused ----------------
__global__ void k_outproj(const bf16* __restrict__ ys, const bf16* __restrict__ xs,
                          const bf16* __restrict__ Z, const float* Dp, const float* ow,
                          float* __restrict__ fused, int dir){
  int b = blockIdx.y;
  int l0 = blockIdx.x * 32;
  const bf16* yd  = ys + ((size_t)dir*BATCH + b)*LLEN*256;
  const bf16* xsd = xs + ((size_t)dir*BATCH + b)*LLEN*256;
  const bf16* zd  = Z  + ((size_t)dir*BATCH + b)*LLEN*256;
  __shared__ float syf[32][256];   // 32 KB
  __shared__ float sow[128][33];   // ~17 KB
  int tid = threadIdx.x;
  float Dv = Dp[tid];
  for (int ll=0; ll<32; ll++){
    size_t l = l0 + ll;
    float yv = b2f(yd[l*256+tid]) + b2f(xsd[l*256+tid])*Dv;
    float zv = b2f(zd[l*256+tid]);
    syf[ll][tid] = yv * (zv/(1.f+__expf(-zv)));
  }
  int c = tid & 127, lh = tid >> 7;
  float acc[16] = {};
  for (int d0=0; d0<256; d0+=32){
    __syncthreads();
    #pragma unroll
    for (int r=0;r<16;r++){
      int idx = tid + r*256;           // 0..4095
      int cc = idx >> 5, dk = idx & 31;
      sow[cc][dk] = ow[cc*256 + d0 + dk];
    }
    __syncthreads();
    for (int dk=0; dk<32; dk++){
      float wv = sow[c][dk];
      #pragma unroll
      for (int i=0;i<16;i++) acc[i] += syf[lh*16+i][d0+dk]*wv;
    }
  }
  for (int i=0;i<16;i++){
    int l = l0 + lh*16 + i;
    int sp = dir ? ((l%56)*56 + l/56) : l;
    fused[((size_t)b*128 + c)*LLEN + sp] += acc[i];
  }
}

// ---------------- mean over spatial ----------------
__global__ void k_mean(const float* __restrict__ fused, float* __restrict__ ymean){
  int bc = blockIdx.x;
  const float* f = fused + (size_t)bc*LLEN;
  float s = 0.f;
  for (int i = threadIdx.x; i < LLEN; i += 256) s += f[i];
  __shared__ float red[256];
  red[threadIdx.x] = s; __syncthreads();
  for (int off=128; off>0; off>>=1){
    if (threadIdx.x < off) red[threadIdx.x] += red[threadIdx.x+off];
    __syncthreads();
  }
  if (threadIdx.x==0) ymean[bc] = red[0]*(1.f/(float)LLEN);
}

// ---------------- channel attention gate ----------------
__global__ void k_gate(const float* __restrict__ ymean, const float* fc1, const float* fc2,
                       float* __restrict__ gate){
  int b = blockIdx.x;
  __shared__ float ym[128], s1[32];
  int tid = threadIdx.x;
  ym[tid] = ymean[b*128+tid];
  __syncthreads();
  if (tid < 32){
    float a = 0.f;
    for (int c=0;c<128;c++) a += ym[c]*fc1[tid*128+c];
    s1[tid] = fmaxf(a, 0.f);
  }
  __syncthreads();
  float a = 0.f;
  #pragma unroll
  for (int j=0;j<32;j++) a += s1[j]*fc2[tid*32+j];
  gate[b*128+tid] = 1.f/(1.f+__expf(-a));
}

// ---------------- final: out = fused * gate + x  (in-place over fused) ----------------
__global__ void k_final(float* __restrict__ fused, const float* __restrict__ gate,
                        const float* __restrict__ x, float* __restrict__ out){
  int i = blockIdx.x*256 + threadIdx.x;
  if (i >= BATCH*128*LLEN) return;
  int bc = i / LLEN;
  float v = fused[i]*gate[bc] + x[i];
  out[i] = v;
}

extern "C" void kernel_launch(void* const* d_in, const int* in_sizes, int n_in,
                              void* d_out, int out_size, void* d_ws, size_t ws_size,
                              hipStream_t stream) {
  const float* x      = (const float*)d_in[0];
  const float* nhw    = (const float*)d_in[1];
  const float* nhb    = (const float*)d_in[2];
  const float* nvw    = (const float*)d_in[3];
  const float* nvb    = (const float*)d_in[4];
  const float* dww    = (const float*)d_in[5];
  const float* dwb    = (const float*)d_in[6];
  const float* pww    = (const float*)d_in[7];
  const float* pwb    = (const float*)d_in[8];
  const float* h_inw  = (const float*)d_in[9];
  const float* h_cw   = (const float*)d_in[10];
  const float* h_cb   = (const float*)d_in[11];
  const float* h_xw   = (const float*)d_in[12];
  const float* h_dtw  = (const float*)d_in[13];
  const float* h_dtb  = (const float*)d_in[14];
  const float* h_Al   = (const float*)d_in[15];
  const float* h_D    = (const float*)d_in[16];
  const float* h_ow   = (const float*)d_in[17];
  const float* v_inw  = (const float*)d_in[18];
  const float* v_cw   = (const float*)d_in[19];
  const float* v_cb   = (const float*)d_in[20];
  const float* v_xw   = (const float*)d_in[21];
  const float* v_dtw  = (const float*)d_in[22];
  const float* v_dtb  = (const float*)d_in[23];
  const float* v_Al   = (const float*)d_in[24];
  const float* v_D    = (const float*)d_in[25];
  const float* v_ow   = (const float*)d_in[26];
  const float* fc1    = (const float*)d_in[27];
  const float* fc2    = (const float*)d_in[28];

  // FUSED lives in d_out (802,816 fp32 = 3,211,264 B = exactly out buffer).
  // k_final is elementwise in-place (reads fused[i], writes out[i]) -> safe.
  float* FUSED = (float*)d_out;
  float* out   = (float*)d_out;

  // Workspace layout (bytes), total ~27.3 MB. Aliases are stream-ordered safe:
  // DT overlays TMP+XLN (both dead after k_inproj); YS overlays XI (dead after k_conv).
  char* base = (char*)d_ws;
  bf16*  TMP   = (bf16*)(base + 0);           // 1,605,632 B
  bf16*  XLN   = (bf16*)(base + 1605632);     // 3,211,264 B (ends 4,816,896)
  bf16*  DT    = (bf16*)(base + 0);           // 6,422,528 B  [alias TMP+XLN]
  bf16*  XI    = (bf16*)(base + 6422528);     // 6,422,528 B
  bf16*  YS    = (bf16*)(base + 6422528);     // 6,422,528 B  [alias XI]
  bf16*  Z     = (bf16*)(base + 12845056);    // 6,422,528 B
  bf16*  XS    = (bf16*)(base + 19267584);    // 6,422,528 B
  float* Bf    = (float*)(base + 25690112);   //   802,816 B
  float* Cf    = (float*)(base + 26492928);   //   802,816 B
  float* YMEAN = (float*)(base + 27295744);   //     1,024 B
  float* GATE  = (float*)(base + 27296768);   //     1,024 B

  k_dwconv_gelu<<<dim3(BATCH*128), dim3(256), 0, stream>>>(x, dww, dwb, TMP);
  k_pw_gemm<<<dim3(49,2,BATCH), dim3(256), 0, stream>>>(TMP, pww, pwb, FUSED);
  k_ln<<<dim3(56,BATCH), dim3(256), 0, stream>>>(x, nhw, nhb, nvw, nvb, XLN);
  k_inproj<<<dim3(98,8,2), dim3(256), 0, stream>>>(XLN, h_inw, v_inw, XI, Z);
  k_conv<<<dim3(98,BATCH,2), dim3(256), 0, stream>>>(XI, h_cw, h_cb, v_cw, v_cb, XS);
  k_xproj<<<dim3(BATCH*LLEN,2), dim3(256), 0, stream>>>(XS, h_xw, v_xw, h_dtw, v_dtw,
                                                        h_dtb, v_dtb, DT, Bf, Cf);
  k_scan<<<dim3(16,BATCH,2), dim3(256), 0, stream>>>(DT, XS, Bf, Cf, h_Al, v_Al, YS);
  k_outproj<<<dim3(98,BATCH), dim3(256), 0, stream>>>(YS, XS, Z, h_D, h_ow, FUSED, 0);
  k_outproj<<<dim3(98,BATCH), dim3(256), 0, stream>>>(YS, XS, Z, v_D, v_ow, FUSED, 1);
  k_mean<<<dim3(BATCH*128), dim3(256), 0, stream>>>(FUSED, YMEAN);
  k_gate<<<dim3(BATCH), dim3(128), 0, stream>>>(YMEAN, fc1, fc2, GATE);
  k_final<<<dim3((BATCH*128*LLEN+255)/256), dim3(256), 0, stream>>>(FUSED, GATE, x, out);
}

// Round 4
// 478.517 us; speedup vs baseline: 2.1672x; 2.1672x over previous
//
#include <hip/hip_runtime.h>
#include <hip/hip_bf16.h>

typedef __hip_bfloat16 bf16;
__device__ __forceinline__ float b2f(bf16 v){ return __bfloat162float(v); }
__device__ __forceinline__ bf16 f2b(float v){ return __float2bfloat16(v); }

#define LLEN 3136
#define BATCH 2
#define NCHUNK 49
#define LC 64

// ---------------- dwconv 3x3 + gelu ----------------
__global__ void k_dwconv_gelu(const float* __restrict__ x, const float* __restrict__ dww,
                              const float* __restrict__ dwb, bf16* __restrict__ tmp){
  int bc = blockIdx.x;            // b*128 + c
  int c = bc & 127;
  const float* xp = x + (size_t)bc*LLEN;
  float w[9];
  #pragma unroll
  for (int i=0;i<9;i++) w[i] = dww[c*9+i];
  float bias = dwb[c];
  for (int p = threadIdx.x; p < LLEN; p += blockDim.x){
    int i = p/56, j = p%56;
    float acc = bias;
    #pragma unroll
    for (int a=0;a<3;a++){
      int ii = i + a - 1;
      if (ii < 0 || ii >= 56) continue;
      #pragma unroll
      for (int bb=0;bb<3;bb++){
        int jj = j + bb - 1;
        if (jj < 0 || jj >= 56) continue;
        acc += w[a*3+bb] * xp[ii*56+jj];
      }
    }
    float g = 0.5f*acc*(1.0f + erff(acc*0.70710678118654752f));
    tmp[(size_t)bc*LLEN + p] = f2b(g);
  }
}

// ---------------- pointwise conv GEMM ----------------
__global__ void k_pw_gemm(const bf16* __restrict__ tmp, const float* __restrict__ pww,
                          const float* __restrict__ pwb, float* __restrict__ fused){
  __shared__ __align__(16) float As[16][68];
  __shared__ __align__(16) float Ws[16][68];
  int b = blockIdx.z;
  int p0 = blockIdx.x * 64;
  int n0 = blockIdx.y * 64;
  const bf16* A = tmp + (size_t)b*128*LLEN;
  int tid = threadIdx.x;
  int tx = tid & 15, ty = tid >> 4;
  float acc[4][4] = {};
  for (int k0 = 0; k0 < 128; k0 += 16){
    #pragma unroll
    for (int r=0;r<4;r++){
      int idx = tid + r*256;
      int k = idx >> 6, m = idx & 63;
      As[k][m] = b2f(A[(size_t)(k0+k)*LLEN + p0 + m]);
    }
    #pragma unroll
    for (int r=0;r<4;r++){
      int idx = tid + r*256;
      int k = idx & 15, n = idx >> 4;
      Ws[k][n] = pww[(n0+n)*128 + k0 + k];
    }
    __syncthreads();
    #pragma unroll
    for (int kk=0;kk<16;kk++){
      float4 av = *reinterpret_cast<const float4*>(&As[kk][ty*4]);
      float4 wv = *reinterpret_cast<const float4*>(&Ws[kk][tx*4]);
      float a4[4] = {av.x,av.y,av.z,av.w};
      float w4[4] = {wv.x,wv.y,wv.z,wv.w};
      #pragma unroll
      for (int i=0;i<4;i++)
        #pragma unroll
        for (int j=0;j<4;j++) acc[i][j] += a4[i]*w4[j];
    }
    __syncthreads();
  }
  #pragma unroll
  for (int j=0;j<4;j++){
    int n = n0 + tx*4 + j;
    float bias = pwb[n];
    #pragma unroll
    for (int i=0;i<4;i++){
      fused[((size_t)b*128 + n)*LLEN + p0 + ty*4 + i] = acc[i][j] + bias;
    }
  }
}

// ---------------- LayerNorm over C, write both direction orderings (bf16) ----------------
__global__ void k_ln(const float* __restrict__ x, const float* nhw_, const float* nhb_,
                     const float* nvw_, const float* nvb_, bf16* __restrict__ xln){
  __shared__ float sx[128][57];
  __shared__ float smean[56], srstd[56];
  __shared__ float wh[128], bh[128], wv_[128], bv_[128];
  int h = blockIdx.x; int b = blockIdx.y;
  int tid = threadIdx.x;
  if (tid < 128){ wh[tid]=nhw_[tid]; bh[tid]=nhb_[tid];
                  wv_[tid]=nvw_[tid]; bv_[tid]=nvb_[tid]; }
  for (int idx = tid; idx < 128*56; idx += 256){
    int c = idx / 56, w = idx % 56;
    sx[c][w] = x[((size_t)(b*128+c))*LLEN + h*56 + w];
  }
  __syncthreads();
  if (tid < 56){
    float s=0.f, s2=0.f;
    for (int c=0;c<128;c++){ float v = sx[c][tid]; s+=v; s2+=v*v; }
    float m = s*(1.f/128.f);
    float var = s2*(1.f/128.f) - m*m;
    smean[tid]=m; srstd[tid]=rsqrtf(var+1e-5f);
  }
  __syncthreads();
  bf16* outh = xln;
  bf16* outv = xln + (size_t)BATCH*LLEN*128;
  for (int idx = tid; idx < 56*128; idx += 256){
    int w = idx >> 7, c = idx & 127;
    float v = (sx[c][w]-smean[w])*srstd[w];
    outh[((size_t)b*LLEN + h*56 + w)*128 + c] = f2b(v*wh[c]+bh[c]);
    outv[((size_t)b*LLEN + w*56 + h)*128 + c] = f2b(v*wv_[c]+bv_[c]);
  }
}

// ---------------- in_proj GEMM ----------------
__global__ void k_inproj(const bf16* __restrict__ xln, const float* __restrict__ hw,
                         const float* __restrict__ vw, bf16* __restrict__ XI, bf16* __restrict__ Z){
  int dir = blockIdx.z;
  const bf16* A = xln + (size_t)dir*BATCH*LLEN*128;
  const float* W = dir ? vw : hw;
  int m0 = blockIdx.x*64, n0 = blockIdx.y*64;
  __shared__ __align__(16) float As[16][68];
  __shared__ __align__(16) float Ws[16][68];
  int tid = threadIdx.x, tx = tid&15, ty = tid>>4;
  float acc[4][4] = {};
  for (int k0=0;k0<128;k0+=16){
    #pragma unroll
    for (int r=0;r<4;r++){
      int idx = tid + r*256;
      int row = idx >> 4, k = idx & 15;
      As[k][row] = b2f(A[(size_t)(m0+row)*128 + k0 + k]);
      Ws[k][row] = W[(size_t)(n0+row)*128 + k0 + k];
    }
    __syncthreads();
    #pragma unroll
    for (int kk=0;kk<16;kk++){
      float4 av = *reinterpret_cast<const float4*>(&As[kk][ty*4]);
      float4 wv = *reinterpret_cast<const float4*>(&Ws[kk][tx*4]);
      float a4[4] = {av.x,av.y,av.z,av.w};
      float w4[4] = {wv.x,wv.y,wv.z,wv.w};
      #pragma unroll
      for (int i=0;i<4;i++)
        #pragma unroll
        for (int j=0;j<4;j++) acc[i][j] += a4[i]*w4[j];
    }
    __syncthreads();
  }
  bf16* dst = (n0 < 256) ? XI : Z;
  int nbase = n0 & 255;
  size_t dslab = (size_t)dir*BATCH*LLEN*256;
  #pragma unroll
  for (int i=0;i<4;i++)
    #pragma unroll
    for (int j=0;j<4;j++)
      dst[dslab + (size_t)(m0+ty*4+i)*256 + nbase + tx*4 + j] = f2b(acc[i][j]);
}

// ---------------- causal depthwise conv1d(k=4) + silu ----------------
__global__ void k_conv(const bf16* __restrict__ XI, const float* hw, const float* hb,
                       const float* vw, const float* vb, bf16* __restrict__ XS){
  int dir = blockIdx.z;
  int b = blockIdx.y;
  int l0 = blockIdx.x * 32;
  const bf16* XId = XI + ((size_t)dir*BATCH + b)*LLEN*256;
  bf16* XSd = XS + ((size_t)dir*BATCH + b)*LLEN*256;
  const float* cw = dir ? vw : hw;
  const float* cb = dir ? vb : hb;
  __shared__ float sxi[35][256];
  int tid = threadIdx.x;
  for (int r = 0; r < 35; r++){
    int l = l0 - 3 + r;
    sxi[r][tid] = (l >= 0) ? b2f(XId[(size_t)l*256 + tid]) : 0.f;
  }
  __syncthreads();
  float w0=cw[tid*4], w1=cw[tid*4+1], w2=cw[tid*4+2], w3=cw[tid*4+3];
  float bias = cb[tid];
  for (int ll=0; ll<32; ll++){
    float acc = bias + w0*sxi[ll][tid] + w1*sxi[ll+1][tid] + w2*sxi[ll+2][tid] + w3*sxi[ll+3][tid];
    float s = acc / (1.f + __expf(-acc));
    XSd[(size_t)(l0+ll)*256 + tid] = f2b(s);
  }
}

// ---------------- xproj -> dbl(40); dt = softplus; B,C extract ----------------
__global__ void k_xproj(const bf16* __restrict__ xs, const float* hx, const float* vx,
                        const float* hdw, const float* vdw, const float* hdb, const float* vdb,
                        bf16* __restrict__ dt, float* __restrict__ Bc, float* __restrict__ Cc){
  int dir = blockIdx.y;
  int m = blockIdx.x;          // b*L + l
  const bf16* xrow = xs + (size_t)dir*BATCH*LLEN*256 + (size_t)m*256;
  const float* xw  = dir ? vx : hx;
  const float* dtw = dir ? vdw : hdw;
  const float* dtb = dir ? vdb : hdb;
  __shared__ float sx[256];
  __shared__ float sdbl[40];
  int tid = threadIdx.x;
  sx[tid] = b2f(xrow[tid]);
  __syncthreads();
  int wv = tid >> 6, lane = tid & 63;
  #pragma unroll
  for (int oi = 0; oi < 10; oi++){
    int o = wv*10 + oi;
    float p = sx[lane]      * xw[o*256+lane]
            + sx[lane+64]   * xw[o*256+lane+64]
            + sx[lane+128]  * xw[o*256+lane+128]
            + sx[lane+192]  * xw[o*256+lane+192];
    #pragma unroll
    for (int off=32; off>0; off>>=1) p += __shfl_down(p, off, 64);
    if (lane == 0) sdbl[o] = p;
  }
  __syncthreads();
  float a = dtb[tid];
  #pragma unroll
  for (int r=0;r<8;r++) a += sdbl[r]*dtw[tid*8+r];
  float sp = (a > 20.f) ? a : __logf(1.f + __expf(a));
  dt[(size_t)dir*BATCH*LLEN*256 + (size_t)m*256 + tid] = f2b(sp);
  if (tid < 16)      Bc[(size_t)dir*BATCH*LLEN*16 + (size_t)m*16 + tid] = sdbl[8+tid];
  else if (tid < 32) Cc[(size_t)dir*BATCH*LLEN*16 + (size_t)m*16 + (tid-16)] = sdbl[24+(tid-16)];
}

// ---------------- chunked selective scan: pass 1 (local scan, P & h_end) ----------------
__global__ void k_scan1(const bf16* __restrict__ dt, const bf16* __restrict__ xs,
                        const float* __restrict__ Bc, const float* hA, const float* vA,
                        float* __restrict__ Pbuf, float* __restrict__ Hbuf){
  int bd = blockIdx.z;           // dir*2+b
  int g  = blockIdx.y;           // channel group 0..15
  int ck = blockIdx.x;           // chunk 0..48
  int l0 = ck*LC;
  const bf16* dtd = dt + (size_t)bd*LLEN*256;
  const bf16* xsd = xs + (size_t)bd*LLEN*256;
  const float* Bd = Bc + (size_t)bd*LLEN*16;
  const float* Alog = (bd >> 1) ? vA : hA;
  int tid = threadIdx.x;
  int dl = tid >> 4, n = tid & 15;
  int d = g*16 + dl;
  float A = -__expf(Alog[d*16+n]);
  __shared__ float sdt[LC][16], sxs[LC][16], sB[LC][16];
  #pragma unroll
  for (int r=0;r<4;r++){
    int idx = tid + r*256;
    int i = idx >> 4, j = idx & 15;
    sdt[i][j] = b2f(dtd[(size_t)(l0+i)*256 + g*16 + j]);
    sxs[i][j] = b2f(xsd[(size_t)(l0+i)*256 + g*16 + j]);
    (&sB[0][0])[idx] = Bd[(size_t)l0*16 + idx];
  }
  __syncthreads();
  float h = 0.f, P = 1.f;
  #pragma unroll 8
  for (int i=0;i<LC;i++){
    float a = sdt[i][dl];
    float u = sxs[i][dl];
    float dA = __expf(a * A);
    h = dA*h + (a*u)*sB[i][n];
    P *= dA;
  }
  size_t sidx = (((size_t)bd*16 + g)*NCHUNK + ck)*256 + tid;
  Pbuf[sidx] = P;
  Hbuf[sidx] = h;
}

// ---------------- pass 2: sequential combine over chunks (in-place h_end -> h_init) ----------------
__global__ void k_scan2(const float* __restrict__ Pbuf, float* __restrict__ Hbuf){
  int q = blockIdx.x;            // bd*16+g, 0..63
  int tid = threadIdx.x;
  float carry = 0.f;
  for (int k=0;k<NCHUNK;k++){
    size_t idx = ((size_t)q*NCHUNK + k)*256 + tid;
    float Pv = Pbuf[idx];
    float He = Hbuf[idx];
    Hbuf[idx] = carry;           // h_init for chunk k
    carry = Pv*carry + He;
  }
}

// ---------------- pass 3: local scan from h_init, emit y ----------------
__global__ void k_scan3(const bf16* __restrict__ dt, const bf16* __restrict__ xs,
                        const float* __restrict__ Bc, const float* __restrict__ Cc,
                        const float* hA, const float* vA,
                        const float* __restrict__ Hbuf, bf16* __restrict__ ys){
  int bd = blockIdx.z;
  int g  = blockIdx.y;
  int ck = blockIdx.x;
  int l0 = ck*LC;
  const bf16* dtd = dt + (size_t)bd*LLEN*256;
  const bf16* xsd = xs + (size_t)bd*LLEN*256;
  const float* Bd = Bc + (size_t)bd*LLEN*16;
  const float* Cd = Cc + (size_t)bd*LLEN*16;
  bf16* yd = ys + (size_t)bd*LLEN*256;
  const float* Alog = (bd >> 1) ? vA : hA;
  int tid = threadIdx.x;
  int dl = tid >> 4, n = tid & 15;
  int d = g*16 + dl;
  float A = -__expf(Alog[d*16+n]);
  __shared__ float sdt[LC][16], sxs[LC][16], sB[LC][16], sC[LC][16];
  __shared__ float sp[LC*256];   // 64 KB: per-step partial products
  #pragma unroll
  for (int r=0;r<4;r++){
    int idx = tid + r*256;
    int i = idx >> 4, j = idx & 15;
    sdt[i][j] = b2f(dtd[(size_t)(l0+i)*256 + g*16 + j]);
    sxs[i][j] = b2f(xsd[(size_t)(l0+i)*256 + g*16 + j]);
    (&sB[0][0])[idx] = Bd[(size_t)l0*16 + idx];
    (&sC[0][0])[idx] = Cd[(size_t)l0*16 + idx];
  }
  size_t sidx = (((size_t)bd*16 + g)*NCHUNK + ck)*256 + tid;
  float h = Hbuf[sidx];
  __syncthreads();
  #pragma unroll 8
  for (int i=0;i<LC;i++){
    float a = sdt[i][dl];
    float u = sxs[i][dl];
    float dA = __expf(a * A);
    h = dA*h + (a*u)*sB[i][n];
    sp[i*256 + tid] = h * sC[i][n];
  }
  __syncthreads();
  // reduce over n (16) for each (i, dl): 1024 outputs, 4 per thread
  #pragma unroll
  for (int r=0;r<4;r++){
    int item = r*256 + tid;      // (i, dl)
    int i = item >> 4, dli = item & 15;
    const float* row = &sp[i*256 + dli*16];
    float s = 0.f;
    #pragma unroll
    for (int nn=0;nn<16;nn++) s += row[nn];
    yd[(size_t)(l0+i)*256 + g*16 + dli] = f2b(s);
  }
}

// ---------------- out_proj + gating, accumulate into fused ----------------
__global__ void k_outproj(const bf16* __restrict__ ys, const bf16* __restrict__ xs,
                          const bf16* __restrict__ Z, const float* Dp, const float* ow,
                          float* __restrict__ fused, int dir){
  int b = blockIdx.y;
  int l0 = blockIdx.x * 32;
  const bf16* yd  = ys + ((size_t)dir*BATCH + b)*LLEN*256;
  const bf16* xsd = xs + ((size_t)dir*BATCH + b)*LLEN*256;
  const bf16* zd  = Z  + ((size_t)dir*BATCH + b)*LLEN*256;
  __shared__ float syf[32][256];   // 32 KB
  __shared__ float sow[128][33];   // ~17 KB
  int tid = threadIdx.x;
  float Dv = Dp[tid];
  for (int ll=0; ll<32; ll++){
    size_t l = l0 + ll;
    float yv = b2f(yd[l*256+tid]) + b2f(xsd[l*256+tid])*Dv;
    float zv = b2f(zd[l*256+tid]);
    syf[ll][tid] = yv * (zv/(1.f+__expf(-zv)));
  }
  int c = tid & 127, lh = tid >> 7;
  float acc[16] = {};
  for (int d0=0; d0<256; d0+=32){
    __syncthreads();
    #pragma unroll
    for (int r=0;r<16;r++){
      int idx = tid + r*256;
      int cc = idx >> 5, dk = idx & 31;
      sow[cc][dk] = ow[cc*256 + d0 + dk];
    }
    __syncthreads();
    for (int dk=0; dk<32; dk++){
      float wv = sow[c][dk];
      #pragma unroll
      for (int i=0;i<16;i++) acc[i] += syf[lh*16+i][d0+dk]*wv;
    }
  }
  for (int i=0;i<16;i++){
    int l = l0 + lh*16 + i;
    int sp2 = dir ? ((l%56)*56 + l/56) : l;
    fused[((size_t)b*128 + c)*LLEN + sp2] += acc[i];
  }
}

// ---------------- mean over spatial ----------------
__global__ void k_mean(const float* __restrict__ fused, float* __restrict__ ymean){
  int bc = blockIdx.x;
  const float* f = fused + (size_t)bc*LLEN;
  float s = 0.f;
  for (int i = threadIdx.x; i < LLEN; i += 256) s += f[i];
  __shared__ float red[256];
  red[threadIdx.x] = s; __syncthreads();
  for (int off=128; off>0; off>>=1){
    if (threadIdx.x < off) red[threadIdx.x] += red[threadIdx.x+off];
    __syncthreads();
  }
  if (threadIdx.x==0) ymean[bc] = red[0]*(1.f/(float)LLEN);
}

// ---------------- channel attention gate ----------------
__global__ void k_gate(const float* __restrict__ ymean, const float* fc1, const float* fc2,
                       float* __restrict__ gate){
  int b = blockIdx.x;
  __shared__ float ym[128], s1[32];
  int tid = threadIdx.x;
  ym[tid] = ymean[b*128+tid];
  __syncthreads();
  if (tid < 32){
    float a = 0.f;
    for (int c=0;c<128;c++) a += ym[c]*fc1[tid*128+c];
    s1[tid] = fmaxf(a, 0.f);
  }
  __syncthreads();
  float a = 0.f;
  #pragma unroll
  for (int j=0;j<32;j++) a += s1[j]*fc2[tid*32+j];
  gate[b*128+tid] = 1.f/(1.f+__expf(-a));
}

// ---------------- final: out = fused * gate + x  (in-place over fused) ----------------
__global__ void k_final(float* __restrict__ fused, const float* __restrict__ gate,
                        const float* __restrict__ x, float* __restrict__ out){
  int i = blockIdx.x*256 + threadIdx.x;
  if (i >= BATCH*128*LLEN) return;
  int bc = i / LLEN;
  float v = fused[i]*gate[bc] + x[i];
  out[i] = v;
}

extern "C" void kernel_launch(void* const* d_in, const int* in_sizes, int n_in,
                              void* d_out, int out_size, void* d_ws, size_t ws_size,
                              hipStream_t stream) {
  const float* x      = (const float*)d_in[0];
  const float* nhw    = (const float*)d_in[1];
  const float* nhb    = (const float*)d_in[2];
  const float* nvw    = (const float*)d_in[3];
  const float* nvb    = (const float*)d_in[4];
  const float* dww    = (const float*)d_in[5];
  const float* dwb    = (const float*)d_in[6];
  const float* pww    = (const float*)d_in[7];
  const float* pwb    = (const float*)d_in[8];
  const float* h_inw  = (const float*)d_in[9];
  const float* h_cw   = (const float*)d_in[10];
  const float* h_cb   = (const float*)d_in[11];
  const float* h_xw   = (const float*)d_in[12];
  const float* h_dtw  = (const float*)d_in[13];
  const float* h_dtb  = (const float*)d_in[14];
  const float* h_Al   = (const float*)d_in[15];
  const float* h_D    = (const float*)d_in[16];
  const float* h_ow   = (const float*)d_in[17];
  const float* v_inw  = (const float*)d_in[18];
  const float* v_cw   = (const float*)d_in[19];
  const float* v_cb   = (const float*)d_in[20];
  const float* v_xw   = (const float*)d_in[21];
  const float* v_dtw  = (const float*)d_in[22];
  const float* v_dtb  = (const float*)d_in[23];
  const float* v_Al   = (const float*)d_in[24];
  const float* v_D    = (const float*)d_in[25];
  const float* v_ow   = (const float*)d_in[26];
  const float* fc1    = (const float*)d_in[27];
  const float* fc2    = (const float*)d_in[28];

  float* FUSED = (float*)d_out;   // FUSED lives in d_out; k_final is in-place elementwise
  float* out   = (float*)d_out;

  // Workspace layout (bytes), high-water ~30.5 MB. Stream-ordered-safe aliases:
  //  DT overlays TMP+XLN (dead after k_inproj)
  //  YS overlays XI (dead after k_conv)
  //  Pbuf overlays first 3.2MB of YS region (P dead after k_scan2, before k_scan3 writes YS)
  char* base = (char*)d_ws;
  bf16*  TMP   = (bf16*)(base + 0);           // 1,605,632 B
  bf16*  XLN   = (bf16*)(base + 1605632);     // 3,211,264 B
  bf16*  DT    = (bf16*)(base + 0);           // 6,422,528 B  [alias TMP+XLN]
  bf16*  XI    = (bf16*)(base + 6422528);     // 6,422,528 B
  bf16*  YS    = (bf16*)(base + 6422528);     // 6,422,528 B  [alias XI]
  float* Pbuf  = (float*)(base + 6422528);    // 3,211,264 B  [alias XI/YS head]
  bf16*  Z     = (bf16*)(base + 12845056);    // 6,422,528 B
  bf16*  XS    = (bf16*)(base + 19267584);    // 6,422,528 B
  float* Bf    = (float*)(base + 25690112);   //   802,816 B
  float* Cf    = (float*)(base + 26492928);   //   802,816 B
  float* Hbuf  = (float*)(base + 27295744);   // 3,211,264 B
  float* YMEAN = (float*)(base + 30507008);   //     1,024 B
  float* GATE  = (float*)(base + 30508032);   //     1,024 B

  k_dwconv_gelu<<<dim3(BATCH*128), dim3(256), 0, stream>>>(x, dww, dwb, TMP);
  k_pw_gemm<<<dim3(49,2,BATCH), dim3(256), 0, stream>>>(TMP, pww, pwb, FUSED);
  k_ln<<<dim3(56,BATCH), dim3(256), 0, stream>>>(x, nhw, nhb, nvw, nvb, XLN);
  k_inproj<<<dim3(98,8,2), dim3(256), 0, stream>>>(XLN, h_inw, v_inw, XI, Z);
  k_conv<<<dim3(98,BATCH,2), dim3(256), 0, stream>>>(XI, h_cw, h_cb, v_cw, v_cb, XS);
  k_xproj<<<dim3(BATCH*LLEN,2), dim3(256), 0, stream>>>(XS, h_xw, v_xw, h_dtw, v_dtw,
                                                        h_dtb, v_dtb, DT, Bf, Cf);
  k_scan1<<<dim3(NCHUNK,16,4), dim3(256), 0, stream>>>(DT, XS, Bf, h_Al, v_Al, Pbuf, Hbuf);
  k_scan2<<<dim3(64), dim3(256), 0, stream>>>(Pbuf, Hbuf);
  k_scan3<<<dim3(NCHUNK,16,4), dim3(256), 0, stream>>>(DT, XS, Bf, Cf, h_Al, v_Al, Hbuf, YS);
  k_outproj<<<dim3(98,BATCH), dim3(256), 0, stream>>>(YS, XS, Z, h_D, h_ow, FUSED, 0);
  k_outproj<<<dim3(98,BATCH), dim3(256), 0, stream>>>(YS, XS, Z, v_D, v_ow, FUSED, 1);
  k_mean<<<dim3(BATCH*128), dim3(256), 0, stream>>>(FUSED, YMEAN);
  k_gate<<<dim3(BATCH), dim3(128), 0, stream>>>(YMEAN, fc1, fc2, GATE);
  k_final<<<dim3((BATCH*128*LLEN+255)/256), dim3(256), 0, stream>>>(FUSED, GATE, x, out);
}

// Round 5
// 377.348 us; speedup vs baseline: 2.7482x; 1.2681x over previous
//
#include <hip/hip_runtime.h>
#include <hip/hip_bf16.h>

typedef __hip_bfloat16 bf16;
__device__ __forceinline__ float b2f(bf16 v){ return __bfloat162float(v); }
__device__ __forceinline__ bf16 f2b(float v){ return __float2bfloat16(v); }

#define LLEN 3136
#define BATCH 2
#define NCHUNK 49
#define LC 64

// ---------------- dwconv 3x3 + gelu ----------------
__global__ void k_dwconv_gelu(const float* __restrict__ x, const float* __restrict__ dww,
                              const float* __restrict__ dwb, bf16* __restrict__ tmp){
  int bc = blockIdx.x;            // b*128 + c
  int c = bc & 127;
  const float* xp = x + (size_t)bc*LLEN;
  float w[9];
  #pragma unroll
  for (int i=0;i<9;i++) w[i] = dww[c*9+i];
  float bias = dwb[c];
  for (int p = threadIdx.x; p < LLEN; p += blockDim.x){
    int i = p/56, j = p%56;
    float acc = bias;
    #pragma unroll
    for (int a=0;a<3;a++){
      int ii = i + a - 1;
      if (ii < 0 || ii >= 56) continue;
      #pragma unroll
      for (int bb=0;bb<3;bb++){
        int jj = j + bb - 1;
        if (jj < 0 || jj >= 56) continue;
        acc += w[a*3+bb] * xp[ii*56+jj];
      }
    }
    float g = 0.5f*acc*(1.0f + erff(acc*0.70710678118654752f));
    tmp[(size_t)bc*LLEN + p] = f2b(g);
  }
}

// ---------------- pointwise conv GEMM ----------------
__global__ void k_pw_gemm(const bf16* __restrict__ tmp, const float* __restrict__ pww,
                          const float* __restrict__ pwb, float* __restrict__ fused){
  __shared__ __align__(16) float As[16][68];
  __shared__ __align__(16) float Ws[16][68];
  int b = blockIdx.z;
  int p0 = blockIdx.x * 64;
  int n0 = blockIdx.y * 64;
  const bf16* A = tmp + (size_t)b*128*LLEN;
  int tid = threadIdx.x;
  int tx = tid & 15, ty = tid >> 4;
  float acc[4][4] = {};
  for (int k0 = 0; k0 < 128; k0 += 16){
    #pragma unroll
    for (int r=0;r<4;r++){
      int idx = tid + r*256;
      int k = idx >> 6, m = idx & 63;
      As[k][m] = b2f(A[(size_t)(k0+k)*LLEN + p0 + m]);
    }
    #pragma unroll
    for (int r=0;r<4;r++){
      int idx = tid + r*256;
      int k = idx & 15, n = idx >> 4;
      Ws[k][n] = pww[(n0+n)*128 + k0 + k];
    }
    __syncthreads();
    #pragma unroll
    for (int kk=0;kk<16;kk++){
      float4 av = *reinterpret_cast<const float4*>(&As[kk][ty*4]);
      float4 wv = *reinterpret_cast<const float4*>(&Ws[kk][tx*4]);
      float a4[4] = {av.x,av.y,av.z,av.w};
      float w4[4] = {wv.x,wv.y,wv.z,wv.w};
      #pragma unroll
      for (int i=0;i<4;i++)
        #pragma unroll
        for (int j=0;j<4;j++) acc[i][j] += a4[i]*w4[j];
    }
    __syncthreads();
  }
  #pragma unroll
  for (int j=0;j<4;j++){
    int n = n0 + tx*4 + j;
    float bias = pwb[n];
    #pragma unroll
    for (int i=0;i<4;i++){
      fused[((size_t)b*128 + n)*LLEN + p0 + ty*4 + i] = acc[i][j] + bias;
    }
  }
}

// ---------------- LayerNorm over C, write both direction orderings (bf16) ----------------
__global__ void k_ln(const float* __restrict__ x, const float* nhw_, const float* nhb_,
                     const float* nvw_, const float* nvb_, bf16* __restrict__ xln){
  __shared__ float sx[128][57];
  __shared__ float smean[56], srstd[56];
  __shared__ float wh[128], bh[128], wv_[128], bv_[128];
  int h = blockIdx.x; int b = blockIdx.y;
  int tid = threadIdx.x;
  if (tid < 128){ wh[tid]=nhw_[tid]; bh[tid]=nhb_[tid];
                  wv_[tid]=nvw_[tid]; bv_[tid]=nvb_[tid]; }
  for (int idx = tid; idx < 128*56; idx += 256){
    int c = idx / 56, w = idx % 56;
    sx[c][w] = x[((size_t)(b*128+c))*LLEN + h*56 + w];
  }
  __syncthreads();
  if (tid < 56){
    float s=0.f, s2=0.f;
    for (int c=0;c<128;c++){ float v = sx[c][tid]; s+=v; s2+=v*v; }
    float m = s*(1.f/128.f);
    float var = s2*(1.f/128.f) - m*m;
    smean[tid]=m; srstd[tid]=rsqrtf(var+1e-5f);
  }
  __syncthreads();
  bf16* outh = xln;
  bf16* outv = xln + (size_t)BATCH*LLEN*128;
  for (int idx = tid; idx < 56*128; idx += 256){
    int w = idx >> 7, c = idx & 127;
    float v = (sx[c][w]-smean[w])*srstd[w];
    outh[((size_t)b*LLEN + h*56 + w)*128 + c] = f2b(v*wh[c]+bh[c]);
    outv[((size_t)b*LLEN + w*56 + h)*128 + c] = f2b(v*wv_[c]+bv_[c]);
  }
}

// ---------------- in_proj GEMM ----------------
__global__ void k_inproj(const bf16* __restrict__ xln, const float* __restrict__ hw,
                         const float* __restrict__ vw, bf16* __restrict__ XI, bf16* __restrict__ Z){
  int dir = blockIdx.z;
  const bf16* A = xln + (size_t)dir*BATCH*LLEN*128;
  const float* W = dir ? vw : hw;
  int m0 = blockIdx.x*64, n0 = blockIdx.y*64;
  __shared__ __align__(16) float As[16][68];
  __shared__ __align__(16) float Ws[16][68];
  int tid = threadIdx.x, tx = tid&15, ty = tid>>4;
  float acc[4][4] = {};
  for (int k0=0;k0<128;k0+=16){
    #pragma unroll
    for (int r=0;r<4;r++){
      int idx = tid + r*256;
      int row = idx >> 4, k = idx & 15;
      As[k][row] = b2f(A[(size_t)(m0+row)*128 + k0 + k]);
      Ws[k][row] = W[(size_t)(n0+row)*128 + k0 + k];
    }
    __syncthreads();
    #pragma unroll
    for (int kk=0;kk<16;kk++){
      float4 av = *reinterpret_cast<const float4*>(&As[kk][ty*4]);
      float4 wv = *reinterpret_cast<const float4*>(&Ws[kk][tx*4]);
      float a4[4] = {av.x,av.y,av.z,av.w};
      float w4[4] = {wv.x,wv.y,wv.z,wv.w};
      #pragma unroll
      for (int i=0;i<4;i++)
        #pragma unroll
        for (int j=0;j<4;j++) acc[i][j] += a4[i]*w4[j];
    }
    __syncthreads();
  }
  bf16* dst = (n0 < 256) ? XI : Z;
  int nbase = n0 & 255;
  size_t dslab = (size_t)dir*BATCH*LLEN*256;
  #pragma unroll
  for (int i=0;i<4;i++)
    #pragma unroll
    for (int j=0;j<4;j++)
      dst[dslab + (size_t)(m0+ty*4+i)*256 + nbase + tx*4 + j] = f2b(acc[i][j]);
}

// ---------------- causal depthwise conv1d(k=4) + silu ----------------
__global__ void k_conv(const bf16* __restrict__ XI, const float* hw, const float* hb,
                       const float* vw, const float* vb, bf16* __restrict__ XS){
  int dir = blockIdx.z;
  int b = blockIdx.y;
  int l0 = blockIdx.x * 32;
  const bf16* XId = XI + ((size_t)dir*BATCH + b)*LLEN*256;
  bf16* XSd = XS + ((size_t)dir*BATCH + b)*LLEN*256;
  const float* cw = dir ? vw : hw;
  const float* cb = dir ? vb : hb;
  __shared__ float sxi[35][256];
  int tid = threadIdx.x;
  for (int r = 0; r < 35; r++){
    int l = l0 - 3 + r;
    sxi[r][tid] = (l >= 0) ? b2f(XId[(size_t)l*256 + tid]) : 0.f;
  }
  __syncthreads();
  float w0=cw[tid*4], w1=cw[tid*4+1], w2=cw[tid*4+2], w3=cw[tid*4+3];
  float bias = cb[tid];
  for (int ll=0; ll<32; ll++){
    float acc = bias + w0*sxi[ll][tid] + w1*sxi[ll+1][tid] + w2*sxi[ll+2][tid] + w3*sxi[ll+3][tid];
    float s = acc / (1.f + __expf(-acc));
    XSd[(size_t)(l0+ll)*256 + tid] = f2b(s);
  }
}

// ---------------- xproj -> dbl(40); dt = softplus; B,C extract ----------------
__global__ void k_xproj(const bf16* __restrict__ xs, const float* hx, const float* vx,
                        const float* hdw, const float* vdw, const float* hdb, const float* vdb,
                        bf16* __restrict__ dt, float* __restrict__ Bc, float* __restrict__ Cc){
  int dir = blockIdx.y;
  int m = blockIdx.x;          // b*L + l
  const bf16* xrow = xs + (size_t)dir*BATCH*LLEN*256 + (size_t)m*256;
  const float* xw  = dir ? vx : hx;
  const float* dtw = dir ? vdw : hdw;
  const float* dtb = dir ? vdb : hdb;
  __shared__ float sx[256];
  __shared__ float sdbl[40];
  int tid = threadIdx.x;
  sx[tid] = b2f(xrow[tid]);
  __syncthreads();
  int wv = tid >> 6, lane = tid & 63;
  #pragma unroll
  for (int oi = 0; oi < 10; oi++){
    int o = wv*10 + oi;
    float p = sx[lane]      * xw[o*256+lane]
            + sx[lane+64]   * xw[o*256+lane+64]
            + sx[lane+128]  * xw[o*256+lane+128]
            + sx[lane+192]  * xw[o*256+lane+192];
    #pragma unroll
    for (int off=32; off>0; off>>=1) p += __shfl_down(p, off, 64);
    if (lane == 0) sdbl[o] = p;
  }
  __syncthreads();
  float a = dtb[tid];
  #pragma unroll
  for (int r=0;r<8;r++) a += sdbl[r]*dtw[tid*8+r];
  float sp = (a > 20.f) ? a : __logf(1.f + __expf(a));
  dt[(size_t)dir*BATCH*LLEN*256 + (size_t)m*256 + tid] = f2b(sp);
  if (tid < 16)      Bc[(size_t)dir*BATCH*LLEN*16 + (size_t)m*16 + tid] = sdbl[8+tid];
  else if (tid < 32) Cc[(size_t)dir*BATCH*LLEN*16 + (size_t)m*16 + (tid-16)] = sdbl[24+(tid-16)];
}

// ---------------- chunked selective scan: pass 1 (local scan, P & h_end) ----------------
__global__ void k_scan1(const bf16* __restrict__ dt, const bf16* __restrict__ xs,
                        const float* __restrict__ Bc, const float* hA, const float* vA,
                        float* __restrict__ Pbuf, float* __restrict__ Hbuf){
  int bd = blockIdx.z;           // dir*2+b
  int g  = blockIdx.y;           // channel group 0..15
  int ck = blockIdx.x;           // chunk 0..48
  int l0 = ck*LC;
  const bf16* dtd = dt + (size_t)bd*LLEN*256;
  const bf16* xsd = xs + (size_t)bd*LLEN*256;
  const float* Bd = Bc + (size_t)bd*LLEN*16;
  const float* Alog = (bd >> 1) ? vA : hA;
  int tid = threadIdx.x;
  int dl = tid >> 4, n = tid & 15;
  int d = g*16 + dl;
  float A = -__expf(Alog[d*16+n]);
  __shared__ float sdt[LC][16], sxs[LC][16], sB[LC][16];
  #pragma unroll
  for (int r=0;r<4;r++){
    int idx = tid + r*256;
    int i = idx >> 4, j = idx & 15;
    sdt[i][j] = b2f(dtd[(size_t)(l0+i)*256 + g*16 + j]);
    sxs[i][j] = b2f(xsd[(size_t)(l0+i)*256 + g*16 + j]);
    (&sB[0][0])[idx] = Bd[(size_t)l0*16 + idx];
  }
  __syncthreads();
  float h = 0.f, P = 1.f;
  #pragma unroll 8
  for (int i=0;i<LC;i++){
    float a = sdt[i][dl];
    float u = sxs[i][dl];
    float dA = __expf(a * A);
    h = dA*h + (a*u)*sB[i][n];
    P *= dA;
  }
  size_t sidx = (((size_t)bd*16 + g)*NCHUNK + ck)*256 + tid;
  Pbuf[sidx] = P;
  Hbuf[sidx] = h;
}

// ---------------- pass 2: sequential combine over chunks (in-place h_end -> h_init) ----------------
__global__ void k_scan2(const float* __restrict__ Pbuf, float* __restrict__ Hbuf){
  int q = blockIdx.x;            // bd*16+g, 0..63
  int tid = threadIdx.x;
  float carry = 0.f;
  for (int k=0;k<NCHUNK;k++){
    size_t idx = ((size_t)q*NCHUNK + k)*256 + tid;
    float Pv = Pbuf[idx];
    float He = Hbuf[idx];
    Hbuf[idx] = carry;           // h_init for chunk k
    carry = Pv*carry + He;
  }
}

// ---------------- pass 3: local scan from h_init, emit y ----------------
__global__ void k_scan3(const bf16* __restrict__ dt, const bf16* __restrict__ xs,
                        const float* __restrict__ Bc, const float* __restrict__ Cc,
                        const float* hA, const float* vA,
                        const float* __restrict__ Hbuf, bf16* __restrict__ ys){
  int bd = blockIdx.z;
  int g  = blockIdx.y;
  int ck = blockIdx.x;
  int l0 = ck*LC;
  const bf16* dtd = dt + (size_t)bd*LLEN*256;
  const bf16* xsd = xs + (size_t)bd*LLEN*256;
  const float* Bd = Bc + (size_t)bd*LLEN*16;
  const float* Cd = Cc + (size_t)bd*LLEN*16;
  bf16* yd = ys + (size_t)bd*LLEN*256;
  const float* Alog = (bd >> 1) ? vA : hA;
  int tid = threadIdx.x;
  int dl = tid >> 4, n = tid & 15;
  int d = g*16 + dl;
  float A = -__expf(Alog[d*16+n]);
  __shared__ float sdt[LC][16], sxs[LC][16], sB[LC][16], sC[LC][16];
  __shared__ float sp[LC*256];   // 64 KB: per-step partial products
  #pragma unroll
  for (int r=0;r<4;r++){
    int idx = tid + r*256;
    int i = idx >> 4, j = idx & 15;
    sdt[i][j] = b2f(dtd[(size_t)(l0+i)*256 + g*16 + j]);
    sxs[i][j] = b2f(xsd[(size_t)(l0+i)*256 + g*16 + j]);
    (&sB[0][0])[idx] = Bd[(size_t)l0*16 + idx];
    (&sC[0][0])[idx] = Cd[(size_t)l0*16 + idx];
  }
  size_t sidx = (((size_t)bd*16 + g)*NCHUNK + ck)*256 + tid;
  float h = Hbuf[sidx];
  __syncthreads();
  #pragma unroll 8
  for (int i=0;i<LC;i++){
    float a = sdt[i][dl];
    float u = sxs[i][dl];
    float dA = __expf(a * A);
    h = dA*h + (a*u)*sB[i][n];
    sp[i*256 + tid] = h * sC[i][n];
  }
  __syncthreads();
  // reduce over n (16) for each (i, dl): 1024 outputs, 4 per thread
  #pragma unroll
  for (int r=0;r<4;r++){
    int item = r*256 + tid;      // (i, dl)
    int i = item >> 4, dli = item & 15;
    const float* row = &sp[i*256 + dli*16];
    float s = 0.f;
    #pragma unroll
    for (int nn=0;nn<16;nn++) s += row[nn];
    yd[(size_t)(l0+i)*256 + g*16 + dli] = f2b(s);
  }
}

// ---------------- YF = (ys + xs*D) * silu(z), bf16 ----------------
__global__ void k_yf(const bf16* __restrict__ ys, const bf16* __restrict__ xs,
                     const bf16* __restrict__ Z, const float* __restrict__ hD,
                     const float* __restrict__ vD, bf16* __restrict__ YF){
  size_t e = (size_t)blockIdx.x*256 + threadIdx.x;   // < 4*LLEN*256
  int d = (int)(e & 255);
  int dir = (int)(e >> 23);                          // e / (2*3136*256) = e / 1605632... use compare
  dir = (e >= (size_t)2*LLEN*256) ? 1 : 0;
  float Dv = dir ? vD[d] : hD[d];
  float yv = b2f(ys[e]) + b2f(xs[e])*Dv;
  float zv = b2f(Z[e]);
  YF[e] = f2b(yv * (zv/(1.f+__expf(-zv))));
}

// ---------------- out_proj GEMM (both dirs), atomically accumulate into fused ----------------
// fused[b][c][sp] += sum_k YF[dir][b][l][k] * ow[c][k];  sp = dir ? transpose(l) : l
__global__ void k_outgemm(const bf16* __restrict__ YF, const float* __restrict__ how,
                          const float* __restrict__ vow, float* __restrict__ fused){
  int dir = blockIdx.z;
  const bf16* A = YF + (size_t)dir*BATCH*LLEN*256;
  const float* W = dir ? vow : how;
  int m0 = blockIdx.x*64, n0 = blockIdx.y*64;
  __shared__ __align__(16) float As[16][68];
  __shared__ __align__(16) float Ws[16][68];
  int tid = threadIdx.x, tx = tid&15, ty = tid>>4;
  float acc[4][4] = {};
  for (int k0=0;k0<256;k0+=16){
    #pragma unroll
    for (int r=0;r<4;r++){
      int idx = tid + r*256;
      int row = idx >> 4, k = idx & 15;
      As[k][row] = b2f(A[(size_t)(m0+row)*256 + k0 + k]);
      Ws[k][row] = W[(size_t)(n0+row)*256 + k0 + k];
    }
    __syncthreads();
    #pragma unroll
    for (int kk=0;kk<16;kk++){
      float4 av = *reinterpret_cast<const float4*>(&As[kk][ty*4]);
      float4 wv = *reinterpret_cast<const float4*>(&Ws[kk][tx*4]);
      float a4[4] = {av.x,av.y,av.z,av.w};
      float w4[4] = {wv.x,wv.y,wv.z,wv.w};
      #pragma unroll
      for (int i=0;i<4;i++)
        #pragma unroll
        for (int j=0;j<4;j++) acc[i][j] += a4[i]*w4[j];
    }
    __syncthreads();
  }
  #pragma unroll
  for (int i=0;i<4;i++){
    int m = m0 + ty*4 + i;
    int b = m / LLEN, l = m % LLEN;
    int sp = dir ? ((l%56)*56 + l/56) : l;
    float* dst = &fused[((size_t)b*128)*LLEN + sp];
    #pragma unroll
    for (int j=0;j<4;j++){
      int c = n0 + tx*4 + j;
      atomicAdd(dst + (size_t)c*LLEN, acc[i][j]);
    }
  }
}

// ---------------- mean over spatial ----------------
__global__ void k_mean(const float* __restrict__ fused, float* __restrict__ ymean){
  int bc = blockIdx.x;
  const float* f = fused + (size_t)bc*LLEN;
  float s = 0.f;
  for (int i = threadIdx.x; i < LLEN; i += 256) s += f[i];
  __shared__ float red[256];
  red[threadIdx.x] = s; __syncthreads();
  for (int off=128; off>0; off>>=1){
    if (threadIdx.x < off) red[threadIdx.x] += red[threadIdx.x+off];
    __syncthreads();
  }
  if (threadIdx.x==0) ymean[bc] = red[0]*(1.f/(float)LLEN);
}

// ---------------- channel attention gate ----------------
__global__ void k_gate(const float* __restrict__ ymean, const float* fc1, const float* fc2,
                       float* __restrict__ gate){
  int b = blockIdx.x;
  __shared__ float ym[128], s1[32];
  int tid = threadIdx.x;
  ym[tid] = ymean[b*128+tid];
  __syncthreads();
  if (tid < 32){
    float a = 0.f;
    for (int c=0;c<128;c++) a += ym[c]*fc1[tid*128+c];
    s1[tid] = fmaxf(a, 0.f);
  }
  __syncthreads();
  float a = 0.f;
  #pragma unroll
  for (int j=0;j<32;j++) a += s1[j]*fc2[tid*32+j];
  gate[b*128+tid] = 1.f/(1.f+__expf(-a));
}

// ---------------- final: out = fused * gate + x  (in-place over fused) ----------------
__global__ void k_final(float* __restrict__ fused, const float* __restrict__ gate,
                        const float* __restrict__ x, float* __restrict__ out){
  int i = blockIdx.x*256 + threadIdx.x;
  if (i >= BATCH*128*LLEN) return;
  int bc = i / LLEN;
  float v = fused[i]*gate[bc] + x[i];
  out[i] = v;
}

extern "C" void kernel_launch(void* const* d_in, const int* in_sizes, int n_in,
                              void* d_out, int out_size, void* d_ws, size_t ws_size,
                              hipStream_t stream) {
  const float* x      = (const float*)d_in[0];
  const float* nhw    = (const float*)d_in[1];
  const float* nhb    = (const float*)d_in[2];
  const float* nvw    = (const float*)d_in[3];
  const float* nvb    = (const float*)d_in[4];
  const float* dww    = (const float*)d_in[5];
  const float* dwb    = (const float*)d_in[6];
  const float* pww    = (const float*)d_in[7];
  const float* pwb    = (const float*)d_in[8];
  const float* h_inw  = (const float*)d_in[9];
  const float* h_cw   = (const float*)d_in[10];
  const float* h_cb   = (const float*)d_in[11];
  const float* h_xw   = (const float*)d_in[12];
  const float* h_dtw  = (const float*)d_in[13];
  const float* h_dtb  = (const float*)d_in[14];
  const float* h_Al   = (const float*)d_in[15];
  const float* h_D    = (const float*)d_in[16];
  const float* h_ow   = (const float*)d_in[17];
  const float* v_inw  = (const float*)d_in[18];
  const float* v_cw   = (const float*)d_in[19];
  const float* v_cb   = (const float*)d_in[20];
  const float* v_xw   = (const float*)d_in[21];
  const float* v_dtw  = (const float*)d_in[22];
  const float* v_dtb  = (const float*)d_in[23];
  const float* v_Al   = (const float*)d_in[24];
  const float* v_D    = (const float*)d_in[25];
  const float* v_ow   = (const float*)d_in[26];
  const float* fc1    = (const float*)d_in[27];
  const float* fc2    = (const float*)d_in[28];

  float* FUSED = (float*)d_out;   // FUSED lives in d_out; k_final is in-place elementwise
  float* out   = (float*)d_out;

  // Workspace layout (bytes), high-water ~30.5 MB. Stream-ordered-safe aliases:
  //  DT overlays TMP+XLN (dead after k_inproj);   YF overlays DT (dead after k_scan3)
  //  YS overlays XI (dead after k_conv);  Pbuf overlays YS head (dead before k_scan3 writes)
  char* base = (char*)d_ws;
  bf16*  TMP   = (bf16*)(base + 0);           // 1,605,632 B
  bf16*  XLN   = (bf16*)(base + 1605632);     // 3,211,264 B
  bf16*  DT    = (bf16*)(base + 0);           // 6,422,528 B  [alias TMP+XLN]
  bf16*  YF    = (bf16*)(base + 0);           // 6,422,528 B  [alias DT]
  bf16*  XI    = (bf16*)(base + 6422528);     // 6,422,528 B
  bf16*  YS    = (bf16*)(base + 6422528);     // 6,422,528 B  [alias XI]
  float* Pbuf  = (float*)(base + 6422528);    // 3,211,264 B  [alias XI/YS head]
  bf16*  Z     = (bf16*)(base + 12845056);    // 6,422,528 B
  bf16*  XS    = (bf16*)(base + 19267584);    // 6,422,528 B
  float* Bf    = (float*)(base + 25690112);   //   802,816 B
  float* Cf    = (float*)(base + 26492928);   //   802,816 B
  float* Hbuf  = (float*)(base + 27295744);   // 3,211,264 B
  float* YMEAN = (float*)(base + 30507008);   //     1,024 B
  float* GATE  = (float*)(base + 30508032);   //     1,024 B

  k_dwconv_gelu<<<dim3(BATCH*128), dim3(256), 0, stream>>>(x, dww, dwb, TMP);
  k_pw_gemm<<<dim3(49,2,BATCH), dim3(256), 0, stream>>>(TMP, pww, pwb, FUSED);
  k_ln<<<dim3(56,BATCH), dim3(256), 0, stream>>>(x, nhw, nhb, nvw, nvb, XLN);
  k_inproj<<<dim3(98,8,2), dim3(256), 0, stream>>>(XLN, h_inw, v_inw, XI, Z);
  k_conv<<<dim3(98,BATCH,2), dim3(256), 0, stream>>>(XI, h_cw, h_cb, v_cw, v_cb, XS);
  k_xproj<<<dim3(BATCH*LLEN,2), dim3(256), 0, stream>>>(XS, h_xw, v_xw, h_dtw, v_dtw,
                                                        h_dtb, v_dtb, DT, Bf, Cf);
  k_scan1<<<dim3(NCHUNK,16,4), dim3(256), 0, stream>>>(DT, XS, Bf, h_Al, v_Al, Pbuf, Hbuf);
  k_scan2<<<dim3(64), dim3(256), 0, stream>>>(Pbuf, Hbuf);
  k_scan3<<<dim3(NCHUNK,16,4), dim3(256), 0, stream>>>(DT, XS, Bf, Cf, h_Al, v_Al, Hbuf, YS);
  k_yf<<<dim3(4*LLEN), dim3(256), 0, stream>>>(YS, XS, Z, h_D, v_D, YF);
  k_outgemm<<<dim3(98,2,2), dim3(256), 0, stream>>>(YF, h_ow, v_ow, FUSED);
  k_mean<<<dim3(BATCH*128), dim3(256), 0, stream>>>(FUSED, YMEAN);
  k_gate<<<dim3(BATCH), dim3(128), 0, stream>>>(YMEAN, fc1, fc2, GATE);
  k_final<<<dim3((BATCH*128*LLEN+255)/256), dim3(256), 0, stream>>>(FUSED, GATE, x, out);
}

// Round 6
// 349.306 us; speedup vs baseline: 2.9688x; 1.0803x over previous
//
#include <hip/hip_runtime.h>
#include <hip/hip_bf16.h>

typedef __hip_bfloat16 bf16;
__device__ __forceinline__ float b2f(bf16 v){ return __bfloat162float(v); }
__device__ __forceinline__ bf16 f2b(float v){ return __float2bfloat16(v); }

#define LLEN 3136
#define BATCH 2
#define NCHUNK 49
#define LC 64

// ---------------- dwconv 3x3 + gelu ----------------
__global__ void k_dwconv_gelu(const float* __restrict__ x, const float* __restrict__ dww,
                              const float* __restrict__ dwb, bf16* __restrict__ tmp){
  int bc = blockIdx.x;            // b*128 + c
  int c = bc & 127;
  const float* xp = x + (size_t)bc*LLEN;
  float w[9];
  #pragma unroll
  for (int i=0;i<9;i++) w[i] = dww[c*9+i];
  float bias = dwb[c];
  for (int p = threadIdx.x; p < LLEN; p += blockDim.x){
    int i = p/56, j = p%56;
    float acc = bias;
    #pragma unroll
    for (int a=0;a<3;a++){
      int ii = i + a - 1;
      if (ii < 0 || ii >= 56) continue;
      #pragma unroll
      for (int bb=0;bb<3;bb++){
        int jj = j + bb - 1;
        if (jj < 0 || jj >= 56) continue;
        acc += w[a*3+bb] * xp[ii*56+jj];
      }
    }
    float g = 0.5f*acc*(1.0f + erff(acc*0.70710678118654752f));
    tmp[(size_t)bc*LLEN + p] = f2b(g);
  }
}

// ---------------- pointwise conv GEMM: 32x64 tiles, register-pipelined ----------------
// fused[b][c][p] = sum_k tmp[b][k][p]*pw[c][k] + pb[c]
__global__ void k_pw_gemm(const bf16* __restrict__ tmp, const float* __restrict__ pww,
                          const float* __restrict__ pwb, float* __restrict__ fused){
  int b = blockIdx.z;
  int p0 = blockIdx.x * 32;
  int n0 = blockIdx.y * 64;
  const bf16* A = tmp + (size_t)b*128*LLEN;
  __shared__ __align__(16) float As[16][36];
  __shared__ __align__(16) float Ws[16][68];
  int tid = threadIdx.x, tx = tid & 15, ty = tid >> 4;
  float acc[2][4] = {};
  float a_r[2], w_r[4];
  // preload k0=0
  #pragma unroll
  for (int r=0;r<2;r++){ int idx = tid + r*256; a_r[r] = b2f(A[(size_t)(idx>>5)*LLEN + p0 + (idx&31)]); }
  #pragma unroll
  for (int r=0;r<4;r++){ int idx = tid + r*256; w_r[r] = pww[(n0 + (idx>>4))*128 + (idx&15)]; }
  for (int k0 = 0; k0 < 128; k0 += 16){
    __syncthreads();
    #pragma unroll
    for (int r=0;r<2;r++){ int idx = tid + r*256; As[idx>>5][idx&31] = a_r[r]; }
    #pragma unroll
    for (int r=0;r<4;r++){ int idx = tid + r*256; Ws[idx&15][idx>>4] = w_r[r]; }
    __syncthreads();
    if (k0 + 16 < 128){
      int kn = k0 + 16;
      #pragma unroll
      for (int r=0;r<2;r++){ int idx = tid + r*256; a_r[r] = b2f(A[(size_t)(kn + (idx>>5))*LLEN + p0 + (idx&31)]); }
      #pragma unroll
      for (int r=0;r<4;r++){ int idx = tid + r*256; w_r[r] = pww[(n0 + (idx>>4))*128 + kn + (idx&15)]; }
    }
    #pragma unroll
    for (int kk=0;kk<16;kk++){
      float2 av = *reinterpret_cast<const float2*>(&As[kk][ty*2]);
      float4 wv = *reinterpret_cast<const float4*>(&Ws[kk][tx*4]);
      float a2[2] = {av.x, av.y};
      float w4[4] = {wv.x, wv.y, wv.z, wv.w};
      #pragma unroll
      for (int i=0;i<2;i++)
        #pragma unroll
        for (int j=0;j<4;j++) acc[i][j] += a2[i]*w4[j];
    }
  }
  #pragma unroll
  for (int j=0;j<4;j++){
    int n = n0 + tx*4 + j;
    float bias = pwb[n];
    #pragma unroll
    for (int i=0;i<2;i++)
      fused[((size_t)b*128 + n)*LLEN + p0 + ty*2 + i] = acc[i][j] + bias;
  }
}

// ---------------- LayerNorm over C, write both direction orderings (bf16) ----------------
__global__ void k_ln(const float* __restrict__ x, const float* nhw_, const float* nhb_,
                     const float* nvw_, const float* nvb_, bf16* __restrict__ xln){
  __shared__ float sx[128][57];
  __shared__ float smean[56], srstd[56];
  __shared__ float wh[128], bh[128], wv_[128], bv_[128];
  int h = blockIdx.x; int b = blockIdx.y;
  int tid = threadIdx.x;
  if (tid < 128){ wh[tid]=nhw_[tid]; bh[tid]=nhb_[tid];
                  wv_[tid]=nvw_[tid]; bv_[tid]=nvb_[tid]; }
  for (int idx = tid; idx < 128*56; idx += 256){
    int c = idx / 56, w = idx % 56;
    sx[c][w] = x[((size_t)(b*128+c))*LLEN + h*56 + w];
  }
  __syncthreads();
  if (tid < 56){
    float s=0.f, s2=0.f;
    for (int c=0;c<128;c++){ float v = sx[c][tid]; s+=v; s2+=v*v; }
    float m = s*(1.f/128.f);
    float var = s2*(1.f/128.f) - m*m;
    smean[tid]=m; srstd[tid]=rsqrtf(var+1e-5f);
  }
  __syncthreads();
  bf16* outh = xln;
  bf16* outv = xln + (size_t)BATCH*LLEN*128;
  for (int idx = tid; idx < 56*128; idx += 256){
    int w = idx >> 7, c = idx & 127;
    float v = (sx[c][w]-smean[w])*srstd[w];
    outh[((size_t)b*LLEN + h*56 + w)*128 + c] = f2b(v*wh[c]+bh[c]);
    outv[((size_t)b*LLEN + w*56 + h)*128 + c] = f2b(v*wv_[c]+bv_[c]);
  }
}

// ---------------- in_proj GEMM ----------------
__global__ void k_inproj(const bf16* __restrict__ xln, const float* __restrict__ hw,
                         const float* __restrict__ vw, bf16* __restrict__ XI, bf16* __restrict__ Z){
  int dir = blockIdx.z;
  const bf16* A = xln + (size_t)dir*BATCH*LLEN*128;
  const float* W = dir ? vw : hw;
  int m0 = blockIdx.x*64, n0 = blockIdx.y*64;
  __shared__ __align__(16) float As[16][68];
  __shared__ __align__(16) float Ws[16][68];
  int tid = threadIdx.x, tx = tid&15, ty = tid>>4;
  float acc[4][4] = {};
  for (int k0=0;k0<128;k0+=16){
    #pragma unroll
    for (int r=0;r<4;r++){
      int idx = tid + r*256;
      int row = idx >> 4, k = idx & 15;
      As[k][row] = b2f(A[(size_t)(m0+row)*128 + k0 + k]);
      Ws[k][row] = W[(size_t)(n0+row)*128 + k0 + k];
    }
    __syncthreads();
    #pragma unroll
    for (int kk=0;kk<16;kk++){
      float4 av = *reinterpret_cast<const float4*>(&As[kk][ty*4]);
      float4 wv = *reinterpret_cast<const float4*>(&Ws[kk][tx*4]);
      float a4[4] = {av.x,av.y,av.z,av.w};
      float w4[4] = {wv.x,wv.y,wv.z,wv.w};
      #pragma unroll
      for (int i=0;i<4;i++)
        #pragma unroll
        for (int j=0;j<4;j++) acc[i][j] += a4[i]*w4[j];
    }
    __syncthreads();
  }
  bf16* dst = (n0 < 256) ? XI : Z;
  int nbase = n0 & 255;
  size_t dslab = (size_t)dir*BATCH*LLEN*256;
  #pragma unroll
  for (int i=0;i<4;i++)
    #pragma unroll
    for (int j=0;j<4;j++)
      dst[dslab + (size_t)(m0+ty*4+i)*256 + nbase + tx*4 + j] = f2b(acc[i][j]);
}

// ---------------- causal depthwise conv1d(k=4) + silu ----------------
__global__ void k_conv(const bf16* __restrict__ XI, const float* hw, const float* hb,
                       const float* vw, const float* vb, bf16* __restrict__ XS){
  int dir = blockIdx.z;
  int b = blockIdx.y;
  int l0 = blockIdx.x * 32;
  const bf16* XId = XI + ((size_t)dir*BATCH + b)*LLEN*256;
  bf16* XSd = XS + ((size_t)dir*BATCH + b)*LLEN*256;
  const float* cw = dir ? vw : hw;
  const float* cb = dir ? vb : hb;
  __shared__ float sxi[35][256];
  int tid = threadIdx.x;
  for (int r = 0; r < 35; r++){
    int l = l0 - 3 + r;
    sxi[r][tid] = (l >= 0) ? b2f(XId[(size_t)l*256 + tid]) : 0.f;
  }
  __syncthreads();
  float w0=cw[tid*4], w1=cw[tid*4+1], w2=cw[tid*4+2], w3=cw[tid*4+3];
  float bias = cb[tid];
  for (int ll=0; ll<32; ll++){
    float acc = bias + w0*sxi[ll][tid] + w1*sxi[ll+1][tid] + w2*sxi[ll+2][tid] + w3*sxi[ll+3][tid];
    float s = acc / (1.f + __expf(-acc));
    XSd[(size_t)(l0+ll)*256 + tid] = f2b(s);
  }
}

// ---------------- xproj -> dbl(40); dt = softplus; B,C extract ----------------
__global__ void k_xproj(const bf16* __restrict__ xs, const float* hx, const float* vx,
                        const float* hdw, const float* vdw, const float* hdb, const float* vdb,
                        bf16* __restrict__ dt, float* __restrict__ Bc, float* __restrict__ Cc){
  int dir = blockIdx.y;
  int m = blockIdx.x;          // b*L + l
  const bf16* xrow = xs + (size_t)dir*BATCH*LLEN*256 + (size_t)m*256;
  const float* xw  = dir ? vx : hx;
  const float* dtw = dir ? vdw : hdw;
  const float* dtb = dir ? vdb : hdb;
  __shared__ float sx[256];
  __shared__ float sdbl[40];
  int tid = threadIdx.x;
  sx[tid] = b2f(xrow[tid]);
  __syncthreads();
  int wv = tid >> 6, lane = tid & 63;
  #pragma unroll
  for (int oi = 0; oi < 10; oi++){
    int o = wv*10 + oi;
    float p = sx[lane]      * xw[o*256+lane]
            + sx[lane+64]   * xw[o*256+lane+64]
            + sx[lane+128]  * xw[o*256+lane+128]
            + sx[lane+192]  * xw[o*256+lane+192];
    #pragma unroll
    for (int off=32; off>0; off>>=1) p += __shfl_down(p, off, 64);
    if (lane == 0) sdbl[o] = p;
  }
  __syncthreads();
  float a = dtb[tid];
  #pragma unroll
  for (int r=0;r<8;r++) a += sdbl[r]*dtw[tid*8+r];
  float sp = (a > 20.f) ? a : __logf(1.f + __expf(a));
  dt[(size_t)dir*BATCH*LLEN*256 + (size_t)m*256 + tid] = f2b(sp);
  if (tid < 16)      Bc[(size_t)dir*BATCH*LLEN*16 + (size_t)m*16 + tid] = sdbl[8+tid];
  else if (tid < 32) Cc[(size_t)dir*BATCH*LLEN*16 + (size_t)m*16 + (tid-16)] = sdbl[24+(tid-16)];
}

// ---------------- chunked selective scan: pass 1 (local scan, P & h_end) ----------------
__global__ void k_scan1(const bf16* __restrict__ dt, const bf16* __restrict__ xs,
                        const float* __restrict__ Bc, const float* hA, const float* vA,
                        float* __restrict__ Pbuf, float* __restrict__ Hbuf){
  int bd = blockIdx.z;           // dir*2+b
  int g  = blockIdx.y;           // channel group 0..15
  int ck = blockIdx.x;           // chunk 0..48
  int l0 = ck*LC;
  const bf16* dtd = dt + (size_t)bd*LLEN*256;
  const bf16* xsd = xs + (size_t)bd*LLEN*256;
  const float* Bd = Bc + (size_t)bd*LLEN*16;
  const float* Alog = (bd >> 1) ? vA : hA;
  int tid = threadIdx.x;
  int dl = tid >> 4, n = tid & 15;
  int d = g*16 + dl;
  float A = -__expf(Alog[d*16+n]);
  __shared__ float sdt[LC][16], sxs[LC][16], sB[LC][16];
  #pragma unroll
  for (int r=0;r<4;r++){
    int idx = tid + r*256;
    int i = idx >> 4, j = idx & 15;
    sdt[i][j] = b2f(dtd[(size_t)(l0+i)*256 + g*16 + j]);
    sxs[i][j] = b2f(xsd[(size_t)(l0+i)*256 + g*16 + j]);
    (&sB[0][0])[idx] = Bd[(size_t)l0*16 + idx];
  }
  __syncthreads();
  float h = 0.f, P = 1.f;
  #pragma unroll 8
  for (int i=0;i<LC;i++){
    float a = sdt[i][dl];
    float u = sxs[i][dl];
    float dA = __expf(a * A);
    h = dA*h + (a*u)*sB[i][n];
    P *= dA;
  }
  size_t sidx = (((size_t)bd*16 + g)*NCHUNK + ck)*256 + tid;
  Pbuf[sidx] = P;
  Hbuf[sidx] = h;
}

// ---------------- pass 2: sequential combine over chunks (in-place h_end -> h_init) ----------------
__global__ void k_scan2(const float* __restrict__ Pbuf, float* __restrict__ Hbuf){
  int q = blockIdx.x;            // bd*16+g, 0..63
  int tid = threadIdx.x;
  float carry = 0.f;
  for (int k=0;k<NCHUNK;k++){
    size_t idx = ((size_t)q*NCHUNK + k)*256 + tid;
    float Pv = Pbuf[idx];
    float He = Hbuf[idx];
    Hbuf[idx] = carry;           // h_init for chunk k
    carry = Pv*carry + He;
  }
}

// ---------------- pass 3: local scan from h_init, emit y ----------------
__global__ void k_scan3(const bf16* __restrict__ dt, const bf16* __restrict__ xs,
                        const float* __restrict__ Bc, const float* __restrict__ Cc,
                        const float* hA, const float* vA,
                        const float* __restrict__ Hbuf, bf16* __restrict__ ys){
  int bd = blockIdx.z;
  int g  = blockIdx.y;
  int ck = blockIdx.x;
  int l0 = ck*LC;
  const bf16* dtd = dt + (size_t)bd*LLEN*256;
  const bf16* xsd = xs + (size_t)bd*LLEN*256;
  const float* Bd = Bc + (size_t)bd*LLEN*16;
  const float* Cd = Cc + (size_t)bd*LLEN*16;
  bf16* yd = ys + (size_t)bd*LLEN*256;
  const float* Alog = (bd >> 1) ? vA : hA;
  int tid = threadIdx.x;
  int dl = tid >> 4, n = tid & 15;
  int d = g*16 + dl;
  float A = -__expf(Alog[d*16+n]);
  __shared__ float sdt[LC][16], sxs[LC][16], sB[LC][16], sC[LC][16];
  __shared__ float sp[LC*256];   // 64 KB: per-step partial products
  #pragma unroll
  for (int r=0;r<4;r++){
    int idx = tid + r*256;
    int i = idx >> 4, j = idx & 15;
    sdt[i][j] = b2f(dtd[(size_t)(l0+i)*256 + g*16 + j]);
    sxs[i][j] = b2f(xsd[(size_t)(l0+i)*256 + g*16 + j]);
    (&sB[0][0])[idx] = Bd[(size_t)l0*16 + idx];
    (&sC[0][0])[idx] = Cd[(size_t)l0*16 + idx];
  }
  size_t sidx = (((size_t)bd*16 + g)*NCHUNK + ck)*256 + tid;
  float h = Hbuf[sidx];
  __syncthreads();
  #pragma unroll 8
  for (int i=0;i<LC;i++){
    float a = sdt[i][dl];
    float u = sxs[i][dl];
    float dA = __expf(a * A);
    h = dA*h + (a*u)*sB[i][n];
    sp[i*256 + tid] = h * sC[i][n];
  }
  __syncthreads();
  // reduce over n (16) for each (i, dl): 1024 outputs, 4 per thread
  #pragma unroll
  for (int r=0;r<4;r++){
    int item = r*256 + tid;      // (i, dl)
    int i = item >> 4, dli = item & 15;
    const float* row = &sp[i*256 + dli*16];
    float s = 0.f;
    #pragma unroll
    for (int nn=0;nn<16;nn++) s += row[nn];
    yd[(size_t)(l0+i)*256 + g*16 + dli] = f2b(s);
  }
}

// ---------------- YF = (ys + xs*D) * silu(z), bf16 ----------------
__global__ void k_yf(const bf16* __restrict__ ys, const bf16* __restrict__ xs,
                     const bf16* __restrict__ Z, const float* __restrict__ hD,
                     const float* __restrict__ vD, bf16* __restrict__ YF){
  size_t e = (size_t)blockIdx.x*256 + threadIdx.x;   // < 4*LLEN*256
  int d = (int)(e & 255);
  int dir = (e >= (size_t)2*LLEN*256) ? 1 : 0;
  float Dv = dir ? vD[d] : hD[d];
  float yv = b2f(ys[e]) + b2f(xs[e])*Dv;
  float zv = b2f(Z[e]);
  YF[e] = f2b(yv * (zv/(1.f+__expf(-zv))));
}

// ---------------- out_proj GEMM: 32x64 tiles, register-pipelined, coalesced OD stores ----------------
// OD[dir][b*l][c] = sum_k YF[dir][b*l][k] * ow[c][k]
__global__ void k_outgemm(const bf16* __restrict__ YF, const float* __restrict__ how,
                          const float* __restrict__ vow, bf16* __restrict__ OD){
  int dir = blockIdx.z;
  const bf16* A = YF + (size_t)dir*BATCH*LLEN*256;
  const float* W = dir ? vow : how;
  bf16* od = OD + (size_t)dir*BATCH*LLEN*128;
  int m0 = blockIdx.x*32, n0 = blockIdx.y*64;
  __shared__ __align__(16) float As[16][36];
  __shared__ __align__(16) float Ws[16][68];
  int tid = threadIdx.x, tx = tid&15, ty = tid>>4;
  float acc[2][4] = {};
  float a_r[2], w_r[4];
  #pragma unroll
  for (int r=0;r<2;r++){ int idx = tid + r*256; a_r[r] = b2f(A[(size_t)(m0 + (idx>>4))*256 + (idx&15)]); }
  #pragma unroll
  for (int r=0;r<4;r++){ int idx = tid + r*256; w_r[r] = W[(size_t)(n0 + (idx>>4))*256 + (idx&15)]; }
  for (int k0=0;k0<256;k0+=16){
    __syncthreads();
    #pragma unroll
    for (int r=0;r<2;r++){ int idx = tid + r*256; As[idx&15][idx>>4] = a_r[r]; }
    #pragma unroll
    for (int r=0;r<4;r++){ int idx = tid + r*256; Ws[idx&15][idx>>4] = w_r[r]; }
    __syncthreads();
    if (k0 + 16 < 256){
      int kn = k0 + 16;
      #pragma unroll
      for (int r=0;r<2;r++){ int idx = tid + r*256; a_r[r] = b2f(A[(size_t)(m0 + (idx>>4))*256 + kn + (idx&15)]); }
      #pragma unroll
      for (int r=0;r<4;r++){ int idx = tid + r*256; w_r[r] = W[(size_t)(n0 + (idx>>4))*256 + kn + (idx&15)]; }
    }
    #pragma unroll
    for (int kk=0;kk<16;kk++){
      float2 av = *reinterpret_cast<const float2*>(&As[kk][ty*2]);
      float4 wv = *reinterpret_cast<const float4*>(&Ws[kk][tx*4]);
      float a2[2] = {av.x, av.y};
      float w4[4] = {wv.x, wv.y, wv.z, wv.w};
      #pragma unroll
      for (int i=0;i<2;i++)
        #pragma unroll
        for (int j=0;j<4;j++) acc[i][j] += a2[i]*w4[j];
    }
  }
  #pragma unroll
  for (int i=0;i<2;i++){
    int m = m0 + ty*2 + i;
    #pragma unroll
    for (int j=0;j<4;j++)
      od[(size_t)m*128 + n0 + tx*4 + j] = f2b(acc[i][j]);
  }
}

// ---------------- combine: fused += OH + OV^T  (per h-row LDS tile) ----------------
__global__ void k_combine(const bf16* __restrict__ OD, float* __restrict__ fused){
  int h = blockIdx.x;            // 0..55
  int b = blockIdx.y;
  __shared__ float sfu[56][129];
  int tid = threadIdx.x;
  const bf16* od0 = OD + (size_t)b*LLEN*128;
  const bf16* od1 = OD + (size_t)(BATCH + b)*LLEN*128;
  #pragma unroll 4
  for (int it=0; it<28; it++){
    int idx = it*256 + tid;      // 0..7167
    int sp = idx >> 7, c = idx & 127;
    float v = b2f(od0[(size_t)(h*56+sp)*128 + c]) + b2f(od1[(size_t)(sp*56+h)*128 + c]);
    sfu[sp][c] = v;
  }
  __syncthreads();
  #pragma unroll 4
  for (int it=0; it<28; it++){
    int lin = it*256 + tid;      // 0..7167 = 128c * 56sp
    int c = lin / 56, sp = lin % 56;
    size_t gi = ((size_t)b*128 + c)*LLEN + h*56 + sp;
    fused[gi] += sfu[sp][c];
  }
}

// ---------------- mean over spatial ----------------
__global__ void k_mean(const float* __restrict__ fused, float* __restrict__ ymean){
  int bc = blockIdx.x;
  const float* f = fused + (size_t)bc*LLEN;
  float s = 0.f;
  for (int i = threadIdx.x; i < LLEN; i += 256) s += f[i];
  __shared__ float red[256];
  red[threadIdx.x] = s; __syncthreads();
  for (int off=128; off>0; off>>=1){
    if (threadIdx.x < off) red[threadIdx.x] += red[threadIdx.x+off];
    __syncthreads();
  }
  if (threadIdx.x==0) ymean[bc] = red[0]*(1.f/(float)LLEN);
}

// ---------------- channel attention gate ----------------
__global__ void k_gate(const float* __restrict__ ymean, const float* fc1, const float* fc2,
                       float* __restrict__ gate){
  int b = blockIdx.x;
  __shared__ float ym[128], s1[32];
  int tid = threadIdx.x;
  ym[tid] = ymean[b*128+tid];
  __syncthreads();
  if (tid < 32){
    float a = 0.f;
    for (int c=0;c<128;c++) a += ym[c]*fc1[tid*128+c];
    s1[tid] = fmaxf(a, 0.f);
  }
  __syncthreads();
  float a = 0.f;
  #pragma unroll
  for (int j=0;j<32;j++) a += s1[j]*fc2[tid*32+j];
  gate[b*128+tid] = 1.f/(1.f+__expf(-a));
}

// ---------------- final: out = fused * gate + x  (in-place over fused) ----------------
__global__ void k_final(float* __restrict__ fused, const float* __restrict__ gate,
                        const float* __restrict__ x, float* __restrict__ out){
  int i = blockIdx.x*256 + threadIdx.x;
  if (i >= BATCH*128*LLEN) return;
  int bc = i / LLEN;
  float v = fused[i]*gate[bc] + x[i];
  out[i] = v;
}

extern "C" void kernel_launch(void* const* d_in, const int* in_sizes, int n_in,
                              void* d_out, int out_size, void* d_ws, size_t ws_size,
                              hipStream_t stream) {
  const float* x      = (const float*)d_in[0];
  const float* nhw    = (const float*)d_in[1];
  const float* nhb    = (const float*)d_in[2];
  const float* nvw    = (const float*)d_in[3];
  const float* nvb    = (const float*)d_in[4];
  const float* dww    = (const float*)d_in[5];
  const float* dwb    = (const float*)d_in[6];
  const float* pww    = (const float*)d_in[7];
  const float* pwb    = (const float*)d_in[8];
  const float* h_inw  = (const float*)d_in[9];
  const float* h_cw   = (const float*)d_in[10];
  const float* h_cb   = (const float*)d_in[11];
  const float* h_xw   = (const float*)d_in[12];
  const float* h_dtw  = (const float*)d_in[13];
  const float* h_dtb  = (const float*)d_in[14];
  const float* h_Al   = (const float*)d_in[15];
  const float* h_D    = (const float*)d_in[16];
  const float* h_ow   = (const float*)d_in[17];
  const float* v_inw  = (const float*)d_in[18];
  const float* v_cw   = (const float*)d_in[19];
  const float* v_cb   = (const float*)d_in[20];
  const float* v_xw   = (const float*)d_in[21];
  const float* v_dtw  = (const float*)d_in[22];
  const float* v_dtb  = (const float*)d_in[23];
  const float* v_Al   = (const float*)d_in[24];
  const float* v_D    = (const float*)d_in[25];
  const float* v_ow   = (const float*)d_in[26];
  const float* fc1    = (const float*)d_in[27];
  const float* fc2    = (const float*)d_in[28];

  float* FUSED = (float*)d_out;   // FUSED lives in d_out; k_final is in-place elementwise
  float* out   = (float*)d_out;

  // Workspace layout (bytes), high-water ~30.5 MB. Stream-ordered-safe aliases:
  //  DT overlays TMP+XLN (dead after k_inproj);  YF overlays DT (dead after k_scan3)
  //  YS overlays XI (dead after k_conv);  Pbuf overlays YS head (dead before k_scan3 writes)
  //  OD overlays YS region (YS dead after k_yf)
  char* base = (char*)d_ws;
  bf16*  TMP   = (bf16*)(base + 0);           // 1,605,632 B
  bf16*  XLN   = (bf16*)(base + 1605632);     // 3,211,264 B
  bf16*  DT    = (bf16*)(base + 0);           // 6,422,528 B  [alias TMP+XLN]
  bf16*  YF    = (bf16*)(base + 0);           // 6,422,528 B  [alias DT]
  bf16*  XI    = (bf16*)(base + 6422528);     // 6,422,528 B
  bf16*  YS    = (bf16*)(base + 6422528);     // 6,422,528 B  [alias XI]
  float* Pbuf  = (float*)(base + 6422528);    // 3,211,264 B  [alias XI/YS head]
  bf16*  OD    = (bf16*)(base + 6422528);     // 3,211,264 B  [alias YS; live after k_yf]
  bf16*  Z     = (bf16*)(base + 12845056);    // 6,422,528 B
  bf16*  XS    = (bf16*)(base + 19267584);    // 6,422,528 B
  float* Bf    = (float*)(base + 25690112);   //   802,816 B
  float* Cf    = (float*)(base + 26492928);   //   802,816 B
  float* Hbuf  = (float*)(base + 27295744);   // 3,211,264 B
  float* YMEAN = (float*)(base + 30507008);   //     1,024 B
  float* GATE  = (float*)(base + 30508032);   //     1,024 B

  k_dwconv_gelu<<<dim3(BATCH*128), dim3(256), 0, stream>>>(x, dww, dwb, TMP);
  k_pw_gemm<<<dim3(98,2,BATCH), dim3(256), 0, stream>>>(TMP, pww, pwb, FUSED);
  k_ln<<<dim3(56,BATCH), dim3(256), 0, stream>>>(x, nhw, nhb, nvw, nvb, XLN);
  k_inproj<<<dim3(98,8,2), dim3(256), 0, stream>>>(XLN, h_inw, v_inw, XI, Z);
  k_conv<<<dim3(98,BATCH,2), dim3(256), 0, stream>>>(XI, h_cw, h_cb, v_cw, v_cb, XS);
  k_xproj<<<dim3(BATCH*LLEN,2), dim3(256), 0, stream>>>(XS, h_xw, v_xw, h_dtw, v_dtw,
                                                        h_dtb, v_dtb, DT, Bf, Cf);
  k_scan1<<<dim3(NCHUNK,16,4), dim3(256), 0, stream>>>(DT, XS, Bf, h_Al, v_Al, Pbuf, Hbuf);
  k_scan2<<<dim3(64), dim3(256), 0, stream>>>(Pbuf, Hbuf);
  k_scan3<<<dim3(NCHUNK,16,4), dim3(256), 0, stream>>>(DT, XS, Bf, Cf, h_Al, v_Al, Hbuf, YS);
  k_yf<<<dim3(4*LLEN), dim3(256), 0, stream>>>(YS, XS, Z, h_D, v_D, YF);
  k_outgemm<<<dim3(196,2,2), dim3(256), 0, stream>>>(YF, h_ow, v_ow, OD);
  k_combine<<<dim3(56,BATCH), dim3(256), 0, stream>>>(OD, FUSED);
  k_mean<<<dim3(BATCH*128), dim3(256), 0, stream>>>(FUSED, YMEAN);
  k_gate<<<dim3(BATCH), dim3(128), 0, stream>>>(YMEAN, fc1, fc2, GATE);
  k_final<<<dim3((BATCH*128*LLEN+255)/256), dim3(256), 0, stream>>>(FUSED, GATE, x, out);
}